// Round 10
// baseline (288.711 us; speedup 1.0000x reference)
//
#include <hip/hip_runtime.h>
#include <hip/hip_bf16.h>
#include <math.h>

#define D 64
#define K_CODES 8192
#define M_QUERIES 32768
#define SLICES 4
#define CODES_PER_SLICE (K_CODES / SLICES)  // 2048
#define CHUNK 64
#define NCHUNK (CODES_PER_SLICE / CHUNK)    // 32 chunks per slice
#define QPB 128                              // queries per block = 4 waves * 32
#define TAU_V 4e-3f                          // gap threshold in v units

typedef __attribute__((ext_vector_type(8))) short bf16x8;
typedef __attribute__((ext_vector_type(4))) float f32x4;
typedef __attribute__((ext_vector_type(16))) float f32x16;

__device__ __forceinline__ unsigned short f2bf(float x) {
    __hip_bfloat16 h = __float2bfloat16(x);
    return *reinterpret_cast<unsigned short*>(&h);
}
__device__ __forceinline__ float bf2f(unsigned short s) {
    __hip_bfloat16 h;
    *reinterpret_cast<unsigned short*>(&h) = s;
    return __bfloat162float(h);
}
__device__ __forceinline__ void gld_lds16(const void* g, void* l) {
    __builtin_amdgcn_global_load_lds(
        (const __attribute__((address_space(1))) void*)g,
        (__attribute__((address_space(3))) void*)l, 16, 0, 0);
}

// ---- K0: split emb into bf16 hi/lo in MFMA-FRAGMENT order ----
// Per 64-code chunk: [u=k-unit 0..7][code-in-chunk 0..63][16B]; byte offset
// chunk*8192 + (u*64 + r)*16 holds code r's elems u*8..u*8+7.
// Also zeroes rescue counter and the loss accumulator (k3 atomicAdds into it).
__global__ __launch_bounds__(256) void k0_split(const float* __restrict__ emb,
                                                unsigned short* __restrict__ e_hi,
                                                unsigned short* __restrict__ e_lo,
                                                float* __restrict__ halfee,
                                                int* __restrict__ ws_cnt,
                                                float* __restrict__ loss_ptr) {
    const int t = threadIdx.x;
    const int chunk = blockIdx.x;
    if (chunk == 0 && t == 0) { *ws_cnt = 0; *loss_ptr = 0.0f; }
    const int u = t & 7;
#pragma unroll
    for (int it = 0; it < 2; ++it) {
        const int r = (t >> 3) + it * 32;           // code within chunk
        const float* src = emb + ((size_t)(chunk * 64 + r) * 64 + u * 8);
        float4 f0 = *(const float4*)(src);
        float4 f1 = *(const float4*)(src + 4);
        float f[8] = {f0.x, f0.y, f0.z, f0.w, f1.x, f1.y, f1.z, f1.w};
        bf16x8 h, lo;
        float s = 0.f;
#pragma unroll
        for (int j = 0; j < 8; ++j) {
            float e = f[j];
            s += e * e;
            unsigned short hh = f2bf(e);
            h[j]  = (short)hh;
            lo[j] = (short)f2bf(e - bf2f(hh));
        }
        size_t off = (size_t)chunk * 8192 + (size_t)(u * 64 + r) * 16;
        *(bf16x8*)((char*)e_hi + off) = h;
        *(bf16x8*)((char*)e_lo + off) = lo;
        s += __shfl_xor(s, 1);
        s += __shfl_xor(s, 2);
        s += __shfl_xor(s, 4);
        if (u == 0) halfee[chunk * 64 + r] = 0.5f * s + 128.0f;
    }
}

// ---- K1: 32x32x16 MFMA scoring v = he' - z.e (bf16 split), packed top-2 ----
// Round-8 staging (hi AND lo fragments in LDS -- r9 showed in-loop global
// fragment reads expose L2 latency). Only the he C-in preload reads global:
// 8 loads/chunk-wave, 2 distinct addresses each (broadcast), consumed once
// per chunk at acc-init. LDS reads/chunk-wave: 24 -> 16.
__global__ __launch_bounds__(256, 1) void k1_mfma(const float* __restrict__ z,
                                                  const unsigned short* __restrict__ e_hi,
                                                  const unsigned short* __restrict__ e_lo,
                                                  const float* __restrict__ halfee,
                                                  float4* __restrict__ ws_part) {
    __shared__ __align__(16) unsigned short ldshi[2][CHUNK * 64];  // 8KB each buf
    __shared__ __align__(16) unsigned short ldslo[2][CHUNK * 64];

    const int tid = threadIdx.x;
    const int wid = tid >> 6;
    const int l   = tid & 63;
    const int col = l & 31;      // query column within wave's 32
    const int hi  = l >> 5;      // k-subgroup selector
    const int slice = blockIdx.y;
    const int chunk0 = slice * NCHUNK;   // global chunk index base

    // this wave's 32 queries -> negated bf16 hi/lo B-fragments
    const int qw0 = blockIdx.x * QPB + wid * 32;
    const int qrow = qw0 + col;
    bf16x8 qh[4], ql[4];
#pragma unroll
    for (int kk = 0; kk < 4; ++kk) {
        const float* src = z + (size_t)qrow * D + kk * 16 + hi * 8;
        float4 f0 = *(const float4*)(src);
        float4 f1 = *(const float4*)(src + 4);
        float f[8] = {f0.x, f0.y, f0.z, f0.w, f1.x, f1.y, f1.z, f1.w};
        bf16x8 h, lo;
#pragma unroll
        for (int j = 0; j < 8; ++j) {
            float x = -f[j];
            unsigned short hh = f2bf(x);
            float r = x - bf2f(hh);
            h[j]  = (short)hh;
            lo[j] = (short)f2bf(r);
        }
        qh[kk] = h;
        ql[kk] = lo;
    }

    float g1 = 1e30f, g2 = 1e30f;
    int   gi = 0x7fffffff;

// async global->LDS staging of hi+lo: 4x gld_lds16 per wave (2KB region each).
#define STAGE(buf, c1)                                                           \
    {                                                                            \
        size_t cb = (size_t)(chunk0 + (c1)) * 8192 + wid * 2048 + l * 16;        \
        const char* ghi = (const char*)e_hi + cb;                                \
        const char* glo = (const char*)e_lo + cb;                                \
        char* dhi = (char*)&ldshi[buf][0] + wid * 2048;                          \
        char* dlo = (char*)&ldslo[buf][0] + wid * 2048;                          \
        gld_lds16(ghi, dhi);                                                     \
        gld_lds16(ghi + 1024, dhi + 1024);                                       \
        gld_lds16(glo, dlo);                                                     \
        gld_lds16(glo + 1024, dlo + 1024);                                       \
    }

#define COMPUTE(bufc, c1, cbase)                                                 \
    {                                                                            \
        const char*  bh  = (const char*)ldshi[bufc];                             \
        const char*  bl  = (const char*)ldslo[bufc];                             \
        const float* bhe = halfee + (size_t)(chunk0 + (c1)) * 64;                \
        f32x16 acc0, acc1;                                                       \
        _Pragma("unroll") for (int g = 0; g < 4; ++g) {                          \
            f32x4 h0 = *(const f32x4*)(bhe + g * 8 + 4 * hi);                    \
            f32x4 h1 = *(const f32x4*)(bhe + 32 + g * 8 + 4 * hi);               \
            acc0[g * 4 + 0] = h0[0]; acc0[g * 4 + 1] = h0[1];                    \
            acc0[g * 4 + 2] = h0[2]; acc0[g * 4 + 3] = h0[3];                    \
            acc1[g * 4 + 0] = h1[0]; acc1[g * 4 + 1] = h1[1];                    \
            acc1[g * 4 + 2] = h1[2]; acc1[g * 4 + 3] = h1[3];                    \
        }                                                                        \
        _Pragma("unroll") for (int kk = 0; kk < 4; ++kk) {                       \
            int a0 = ((kk * 2 + hi) * 64 + col) * 16;   /* lane-contiguous */    \
            bf16x8 ah0 = *(const bf16x8*)(bh + a0);                              \
            bf16x8 ah1 = *(const bf16x8*)(bh + a0 + 512);                        \
            bf16x8 al0 = *(const bf16x8*)(bl + a0);                              \
            bf16x8 al1 = *(const bf16x8*)(bl + a0 + 512);                        \
            acc0 = __builtin_amdgcn_mfma_f32_32x32x16_bf16(ah0, qh[kk], acc0, 0, 0, 0); \
            acc1 = __builtin_amdgcn_mfma_f32_32x32x16_bf16(ah1, qh[kk], acc1, 0, 0, 0); \
            acc0 = __builtin_amdgcn_mfma_f32_32x32x16_bf16(ah0, ql[kk], acc0, 0, 0, 0); \
            acc1 = __builtin_amdgcn_mfma_f32_32x32x16_bf16(ah1, ql[kk], acc1, 0, 0, 0); \
            acc0 = __builtin_amdgcn_mfma_f32_32x32x16_bf16(al0, qh[kk], acc0, 0, 0, 0); \
            acc1 = __builtin_amdgcn_mfma_f32_32x32x16_bf16(al1, qh[kk], acc1, 0, 0, 0); \
        }                                                                        \
        float m1p = 1e30f, m2p = 1e30f;                                          \
        _Pragma("unroll") for (int r = 0; r < 16; ++r) {                         \
            float vp0 = __int_as_float((__float_as_int(acc0[r]) & 0xFFFFFFE0) | r); \
            m2p = __builtin_amdgcn_fmed3f(vp0, m1p, m2p);                        \
            m1p = fminf(m1p, vp0);                                               \
            float vp1 = __int_as_float((__float_as_int(acc1[r]) & 0xFFFFFFE0) | (16 + r)); \
            m2p = __builtin_amdgcn_fmed3f(vp1, m1p, m2p);                        \
            m1p = fminf(m1p, vp1);                                               \
        }                                                                        \
        int p1 = __float_as_int(m1p) & 31;                                       \
        int rr = p1 & 15;                                                        \
        int code = (cbase) + (p1 >> 4) * 32 + (rr & 3) + 8 * (rr >> 2) + 4 * hi; \
        bool lt = m1p < g1;                                                      \
        g2 = fminf(lt ? g1 : g2, lt ? m2p : m1p);                                \
        g1 = lt ? m1p : g1;                                                      \
        gi = lt ? code : gi;                                                     \
    }

    STAGE(0, 0);
    __syncthreads();   // vmcnt(0) drain (4 loads) before first compute
    for (int c = 0; c < NCHUNK; ++c) {
        const int cur = c & 1;
        if (c + 1 < NCHUNK) STAGE(cur ^ 1, c + 1);
        COMPUTE(cur, c, slice * CODES_PER_SLICE + c * CHUNK);
        __syncthreads();
    }

    // lanes l and l^32 share a query column, hold disjoint code rows
    {
        float o1 = __shfl_xor(g1, 32);
        float o2 = __shfl_xor(g2, 32);
        int   oi = __shfl_xor(gi, 32);
        bool  take = (o1 < g1) || (o1 == g1 && oi < gi);
        float n2   = take ? fminf(o2, g1) : fminf(g2, o1);
        g1 = take ? o1 : g1;
        gi = take ? oi : gi;
        g2 = n2;
        if (l < 32) {
            int q = qw0 + col;
            ws_part[(size_t)q * SLICES + slice] =
                make_float4(g1, g2, __int_as_float(gi), 0.f);
        }
    }
#undef STAGE
#undef COMPUTE
}

// ---- K1b: merge slices, flag near-ties ----
__global__ __launch_bounds__(256) void k1b_merge(const float4* __restrict__ ws_part,
                                                 int* __restrict__ ws_idx,
                                                 int* __restrict__ ws_cnt,
                                                 int* __restrict__ ws_list) {
    int q = blockIdx.x * blockDim.x + threadIdx.x;
    float m1 = 1e30f, m2 = 1e30f;
    int   i1 = 0x7fffffff;
#pragma unroll
    for (int s = 0; s < SLICES; ++s) {
        float4 p = ws_part[(size_t)q * SLICES + s];
        float v1 = p.x, v2 = p.y;
        int   vi = __float_as_int(p.z);
        if (v1 < m1 || (v1 == m1 && vi < i1)) { m2 = fminf(m1, v2); m1 = v1; i1 = vi; }
        else                                  { m2 = fminf(m2, v1); }
    }
    ws_idx[q] = i1;
    if (m2 - m1 < TAU_V) {
        int r = atomicAdd(ws_cnt, 1);
        ws_list[r] = q;
    }
}

// ---- K2: fp64 exact rescan for near-tie queries ----
__global__ __launch_bounds__(256) void k2_rescue(const float* __restrict__ z,
                                                 const float* __restrict__ emb,
                                                 const int* __restrict__ ws_cnt,
                                                 const int* __restrict__ ws_list,
                                                 int* __restrict__ ws_idx) {
    __shared__ float  zrow[D];
    __shared__ double rv[256];
    __shared__ int    ri[256];
    const int cnt = *ws_cnt;
    for (int r = blockIdx.x; r < cnt; r += gridDim.x) {
        const int q = ws_list[r];
        __syncthreads();
        if (threadIdx.x < D) zrow[threadIdx.x] = z[(size_t)q * D + threadIdx.x];
        __syncthreads();
        double best = 1e300;
        int    bi   = 0x7fffffff;
        for (int c = threadIdx.x; c < K_CODES; c += 256) {
            const float4* er = (const float4*)(emb + (size_t)c * D);
            double acc = 0.0;
#pragma unroll
            for (int k = 0; k < 16; ++k) {
                float4 e  = er[k];
                double d0 = (double)zrow[4 * k + 0] - (double)e.x;
                double d1 = (double)zrow[4 * k + 1] - (double)e.y;
                double d2 = (double)zrow[4 * k + 2] - (double)e.z;
                double d3 = (double)zrow[4 * k + 3] - (double)e.w;
                acc += d0 * d0 + d1 * d1 + d2 * d2 + d3 * d3;
            }
            if (acc < best) { best = acc; bi = c; }
        }
        rv[threadIdx.x] = best;
        ri[threadIdx.x] = bi;
        __syncthreads();
        for (int s = 128; s > 0; s >>= 1) {
            if (threadIdx.x < s) {
                double ov = rv[threadIdx.x + s];
                int    oi = ri[threadIdx.x + s];
                if (ov < rv[threadIdx.x] || (ov == rv[threadIdx.x] && oi < ri[threadIdx.x])) {
                    rv[threadIdx.x] = ov;
                    ri[threadIdx.x] = oi;
                }
            }
            __syncthreads();
        }
        if (threadIdx.x == 0) ws_idx[q] = ri[0];
        __syncthreads();
    }
}

// ---- K3: gather z_q, emit idx as float, fused loss via pre-scaled atomicAdd ----
// (k0 zeroes the loss slot each launch; f32 atomic ordering noise ~1e-3 vs
//  threshold 163 -- irrelevant.)
__global__ __launch_bounds__(256) void k3_gather(const float* __restrict__ emb,
                                                 const float* __restrict__ z,
                                                 const int* __restrict__ ws_idx,
                                                 float* __restrict__ out,
                                                 float* __restrict__ loss_ptr) {
    __shared__ float sb[256];
    int g = blockIdx.x * 256 + threadIdx.x;
    int q = g >> 6, d = g & 63;
    int id = ws_idx[q];
    float e = emb[(size_t)id * D + d];
    out[g] = e;
    if (d == 0) out[(size_t)M_QUERIES * D + q] = (float)id;
    float df = e - z[g];
    sb[threadIdx.x] = df * df;
    __syncthreads();
    for (int s = 128; s > 0; s >>= 1) {
        if (threadIdx.x < s) sb[threadIdx.x] += sb[threadIdx.x + s];
        __syncthreads();
    }
    if (threadIdx.x == 0)
        atomicAdd(loss_ptr, sb[0] * (1.25f / (float)((size_t)M_QUERIES * D)));
}

extern "C" void kernel_launch(void* const* d_in, const int* in_sizes, int n_in,
                              void* d_out, int out_size, void* d_ws, size_t ws_size,
                              hipStream_t stream) {
    const float* z   = (const float*)d_in[0];
    const float* emb = (const float*)d_in[1];
    float* out = (float*)d_out;
    char*  ws  = (char*)d_ws;

    unsigned short* e_hi    = (unsigned short*)(ws);                    // 1 MB
    unsigned short* e_lo    = (unsigned short*)(ws + 1048576);          // 1 MB
    float*          halfee  = (float*)(ws + 2097152);                   // 32 KB
    float4*         ws_part = (float4*)(ws + 2129920);                  // 2 MB
    int*            ws_idx  = (int*)(ws + 2129920 + 2097152);           // 128 KB
    int*            ws_cnt  = (int*)(ws + 2129920 + 2097152 + 131072);  // 64 B
    int*            ws_list = (int*)(ws + 2129920 + 2097152 + 131136);  // 128 KB

    float* loss_ptr = out + (size_t)M_QUERIES * D + M_QUERIES;

    k0_split<<<K_CODES / 64, 256, 0, stream>>>(emb, e_hi, e_lo, halfee, ws_cnt, loss_ptr);

    dim3 g1(M_QUERIES / QPB, SLICES);
    k1_mfma<<<g1, 256, 0, stream>>>(z, e_hi, e_lo, halfee, ws_part);

    k1b_merge<<<M_QUERIES / 256, 256, 0, stream>>>(ws_part, ws_idx, ws_cnt, ws_list);

    k2_rescue<<<256, 256, 0, stream>>>(z, emb, ws_cnt, ws_list, ws_idx);

    k3_gather<<<(M_QUERIES * D) / 256, 256, 0, stream>>>(emb, z, ws_idx, out, loss_ptr);
}

// Round 11
// 198.745 us; speedup vs baseline: 1.4527x; 1.4527x over previous
//
#include <hip/hip_runtime.h>
#include <hip/hip_bf16.h>
#include <math.h>

#define D 64
#define K_CODES 8192
#define M_QUERIES 32768
#define SLICES 4
#define CODES_PER_SLICE (K_CODES / SLICES)  // 2048
#define CHUNK 64
#define NCHUNK (CODES_PER_SLICE / CHUNK)    // 32 chunks per slice
#define QPB 128                              // queries per block = 4 waves * 32
#define TAU_V 4e-3f                          // gap threshold in v units

typedef __attribute__((ext_vector_type(8))) short bf16x8;
typedef __attribute__((ext_vector_type(4))) float f32x4;
typedef __attribute__((ext_vector_type(16))) float f32x16;

__device__ __forceinline__ unsigned short f2bf(float x) {
    __hip_bfloat16 h = __float2bfloat16(x);
    return *reinterpret_cast<unsigned short*>(&h);
}
__device__ __forceinline__ float bf2f(unsigned short s) {
    __hip_bfloat16 h;
    *reinterpret_cast<unsigned short*>(&h) = s;
    return __bfloat162float(h);
}
__device__ __forceinline__ void gld_lds16(const void* g, void* l) {
    __builtin_amdgcn_global_load_lds(
        (const __attribute__((address_space(1))) void*)g,
        (__attribute__((address_space(3))) void*)l, 16, 0, 0);
}
__device__ __forceinline__ void gld_lds4(const void* g, void* l) {
    __builtin_amdgcn_global_load_lds(
        (const __attribute__((address_space(1))) void*)g,
        (__attribute__((address_space(3))) void*)l, 4, 0, 0);
}

// ---- K0: split emb into bf16 hi/lo in MFMA-FRAGMENT order ----
// Per 64-code chunk: [u=k-unit 0..7][code-in-chunk 0..63][16B]; byte offset
// chunk*8192 + (u*64 + r)*16 holds code r's elems u*8..u*8+7.
__global__ __launch_bounds__(256) void k0_split(const float* __restrict__ emb,
                                                unsigned short* __restrict__ e_hi,
                                                unsigned short* __restrict__ e_lo,
                                                float* __restrict__ halfee,
                                                int* __restrict__ ws_cnt) {
    const int t = threadIdx.x;
    const int chunk = blockIdx.x;
    if (chunk == 0 && t == 0) *ws_cnt = 0;
    const int u = t & 7;
#pragma unroll
    for (int it = 0; it < 2; ++it) {
        const int r = (t >> 3) + it * 32;           // code within chunk
        const float* src = emb + ((size_t)(chunk * 64 + r) * 64 + u * 8);
        float4 f0 = *(const float4*)(src);
        float4 f1 = *(const float4*)(src + 4);
        float f[8] = {f0.x, f0.y, f0.z, f0.w, f1.x, f1.y, f1.z, f1.w};
        bf16x8 h, lo;
        float s = 0.f;
#pragma unroll
        for (int j = 0; j < 8; ++j) {
            float e = f[j];
            s += e * e;
            unsigned short hh = f2bf(e);
            h[j]  = (short)hh;
            lo[j] = (short)f2bf(e - bf2f(hh));
        }
        size_t off = (size_t)chunk * 8192 + (size_t)(u * 64 + r) * 16;
        *(bf16x8*)((char*)e_hi + off) = h;
        *(bf16x8*)((char*)e_lo + off) = lo;
        s += __shfl_xor(s, 1);
        s += __shfl_xor(s, 2);
        s += __shfl_xor(s, 4);
        if (u == 0) halfee[chunk * 64 + r] = 0.5f * s + 128.0f;
    }
}

// ---- K1: 32x32x16 MFMA scoring v = he' - z.e (bf16 split), packed top-2 ----
// Round-8 staging (hi+lo+he all global_load_lds -> LDS) + counted-vmcnt
// pipeline (T4): stage 2 chunks ahead, wait vmcnt(5) (leave next chunk's 5
// loads in flight) + raw s_barrier instead of __syncthreads' vmcnt(0) drain.
__global__ __launch_bounds__(256, 1) void k1_mfma(const float* __restrict__ z,
                                                  const unsigned short* __restrict__ e_hi,
                                                  const unsigned short* __restrict__ e_lo,
                                                  const float* __restrict__ halfee,
                                                  float4* __restrict__ ws_part) {
    __shared__ __align__(16) unsigned short ldshi[2][CHUNK * 64];  // 8KB each buf
    __shared__ __align__(16) unsigned short ldslo[2][CHUNK * 64];
    __shared__ __align__(16) float ldshe[2][CHUNK];                // 256B each

    const int tid = threadIdx.x;
    const int wid = tid >> 6;
    const int l   = tid & 63;
    const int col = l & 31;      // query column within wave's 32
    const int hi  = l >> 5;      // k-subgroup selector
    const int slice = blockIdx.y;
    const int chunk0 = slice * NCHUNK;   // global chunk index base

    // this wave's 32 queries -> negated bf16 hi/lo B-fragments
    const int qw0 = blockIdx.x * QPB + wid * 32;
    const int qrow = qw0 + col;
    bf16x8 qh[4], ql[4];
#pragma unroll
    for (int kk = 0; kk < 4; ++kk) {
        const float* src = z + (size_t)qrow * D + kk * 16 + hi * 8;
        float4 f0 = *(const float4*)(src);
        float4 f1 = *(const float4*)(src + 4);
        float f[8] = {f0.x, f0.y, f0.z, f0.w, f1.x, f1.y, f1.z, f1.w};
        bf16x8 h, lo;
#pragma unroll
        for (int j = 0; j < 8; ++j) {
            float x = -f[j];
            unsigned short hh = f2bf(x);
            float r = x - bf2f(hh);
            h[j]  = (short)hh;
            lo[j] = (short)f2bf(r);
        }
        qh[kk] = h;
        ql[kk] = lo;
    }

    float g1 = 1e30f, g2 = 1e30f;
    int   gi = 0x7fffffff;

// 5 loads/wave/stage, uniform across waves (he staged redundantly by all 4
// waves -> same data, benign; keeps the vmcnt constant).
#define STAGE(buf, c1)                                                           \
    {                                                                            \
        size_t cb = (size_t)(chunk0 + (c1)) * 8192 + wid * 2048 + l * 16;        \
        const char* ghi = (const char*)e_hi + cb;                                \
        const char* glo = (const char*)e_lo + cb;                                \
        char* dhi = (char*)&ldshi[buf][0] + wid * 2048;                          \
        char* dlo = (char*)&ldslo[buf][0] + wid * 2048;                          \
        gld_lds16(ghi, dhi);                                                     \
        gld_lds16(ghi + 1024, dhi + 1024);                                       \
        gld_lds16(glo, dlo);                                                     \
        gld_lds16(glo + 1024, dlo + 1024);                                       \
        gld_lds4((const char*)halfee + (size_t)(chunk0 + (c1)) * 256 + l * 4,    \
                 (char*)&ldshe[buf][0]);                                         \
    }

#define COMPUTE(bufc, cbase)                                                     \
    {                                                                            \
        const char*  bh  = (const char*)ldshi[bufc];                             \
        const char*  bl  = (const char*)ldslo[bufc];                             \
        const float* bhe = ldshe[bufc];                                          \
        f32x16 acc0, acc1;                                                       \
        _Pragma("unroll") for (int g = 0; g < 4; ++g) {                          \
            f32x4 h0 = *(const f32x4*)(bhe + g * 8 + 4 * hi);                    \
            f32x4 h1 = *(const f32x4*)(bhe + 32 + g * 8 + 4 * hi);               \
            acc0[g * 4 + 0] = h0[0]; acc0[g * 4 + 1] = h0[1];                    \
            acc0[g * 4 + 2] = h0[2]; acc0[g * 4 + 3] = h0[3];                    \
            acc1[g * 4 + 0] = h1[0]; acc1[g * 4 + 1] = h1[1];                    \
            acc1[g * 4 + 2] = h1[2]; acc1[g * 4 + 3] = h1[3];                    \
        }                                                                        \
        _Pragma("unroll") for (int kk = 0; kk < 4; ++kk) {                       \
            int a0 = ((kk * 2 + hi) * 64 + col) * 16;   /* lane-contiguous */    \
            bf16x8 ah0 = *(const bf16x8*)(bh + a0);                              \
            bf16x8 ah1 = *(const bf16x8*)(bh + a0 + 512);                        \
            bf16x8 al0 = *(const bf16x8*)(bl + a0);                              \
            bf16x8 al1 = *(const bf16x8*)(bl + a0 + 512);                        \
            acc0 = __builtin_amdgcn_mfma_f32_32x32x16_bf16(ah0, qh[kk], acc0, 0, 0, 0); \
            acc1 = __builtin_amdgcn_mfma_f32_32x32x16_bf16(ah1, qh[kk], acc1, 0, 0, 0); \
            acc0 = __builtin_amdgcn_mfma_f32_32x32x16_bf16(ah0, ql[kk], acc0, 0, 0, 0); \
            acc1 = __builtin_amdgcn_mfma_f32_32x32x16_bf16(ah1, ql[kk], acc1, 0, 0, 0); \
            acc0 = __builtin_amdgcn_mfma_f32_32x32x16_bf16(al0, qh[kk], acc0, 0, 0, 0); \
            acc1 = __builtin_amdgcn_mfma_f32_32x32x16_bf16(al1, qh[kk], acc1, 0, 0, 0); \
        }                                                                        \
        float m1p = 1e30f, m2p = 1e30f;                                          \
        _Pragma("unroll") for (int r = 0; r < 16; ++r) {                         \
            float vp0 = __int_as_float((__float_as_int(acc0[r]) & 0xFFFFFFE0) | r); \
            m2p = __builtin_amdgcn_fmed3f(vp0, m1p, m2p);                        \
            m1p = fminf(m1p, vp0);                                               \
            float vp1 = __int_as_float((__float_as_int(acc1[r]) & 0xFFFFFFE0) | (16 + r)); \
            m2p = __builtin_amdgcn_fmed3f(vp1, m1p, m2p);                        \
            m1p = fminf(m1p, vp1);                                               \
        }                                                                        \
        int p1 = __float_as_int(m1p) & 31;                                       \
        int rr = p1 & 15;                                                        \
        int code = (cbase) + (p1 >> 4) * 32 + (rr & 3) + 8 * (rr >> 2) + 4 * hi; \
        bool lt = m1p < g1;                                                      \
        g2 = fminf(lt ? g1 : g2, lt ? m2p : m1p);                                \
        g1 = lt ? m1p : g1;                                                      \
        gi = lt ? code : gi;                                                     \
    }

    // prologue: 2 chunks in flight (10 outstanding loads/wave)
    STAGE(0, 0);
    STAGE(1, 1);
    for (int c = 0; c < NCHUNK - 1; ++c) {
        // wait for chunk c's 5 loads; chunk c+1's 5 stay in flight
        asm volatile("s_waitcnt vmcnt(5)" ::: "memory");
        __builtin_amdgcn_s_barrier();            // all waves' buf[c&1] ready
        COMPUTE(c & 1, slice * CODES_PER_SLICE + c * CHUNK);
        asm volatile("s_waitcnt lgkmcnt(0)" ::: "memory");  // LDS reads done
        __builtin_amdgcn_s_barrier();            // buf[c&1] free to overwrite
        if (c + 2 < NCHUNK) STAGE(c & 1, c + 2);
    }
    asm volatile("s_waitcnt vmcnt(0)" ::: "memory");
    __builtin_amdgcn_s_barrier();
    COMPUTE((NCHUNK - 1) & 1, slice * CODES_PER_SLICE + (NCHUNK - 1) * CHUNK);

    // lanes l and l^32 share a query column, hold disjoint code rows
    {
        float o1 = __shfl_xor(g1, 32);
        float o2 = __shfl_xor(g2, 32);
        int   oi = __shfl_xor(gi, 32);
        bool  take = (o1 < g1) || (o1 == g1 && oi < gi);
        float n2   = take ? fminf(o2, g1) : fminf(g2, o1);
        g1 = take ? o1 : g1;
        gi = take ? oi : gi;
        g2 = n2;
        if (l < 32) {
            int q = qw0 + col;
            ws_part[(size_t)q * SLICES + slice] =
                make_float4(g1, g2, __int_as_float(gi), 0.f);
        }
    }
#undef STAGE
#undef COMPUTE
}

// ---- K1b: merge slices, flag near-ties ----
__global__ __launch_bounds__(256) void k1b_merge(const float4* __restrict__ ws_part,
                                                 int* __restrict__ ws_idx,
                                                 int* __restrict__ ws_cnt,
                                                 int* __restrict__ ws_list) {
    int q = blockIdx.x * blockDim.x + threadIdx.x;
    float m1 = 1e30f, m2 = 1e30f;
    int   i1 = 0x7fffffff;
#pragma unroll
    for (int s = 0; s < SLICES; ++s) {
        float4 p = ws_part[(size_t)q * SLICES + s];
        float v1 = p.x, v2 = p.y;
        int   vi = __float_as_int(p.z);
        if (v1 < m1 || (v1 == m1 && vi < i1)) { m2 = fminf(m1, v2); m1 = v1; i1 = vi; }
        else                                  { m2 = fminf(m2, v1); }
    }
    ws_idx[q] = i1;
    if (m2 - m1 < TAU_V) {
        int r = atomicAdd(ws_cnt, 1);
        ws_list[r] = q;
    }
}

// ---- K2: fp64 exact rescan for near-tie queries ----
__global__ __launch_bounds__(256) void k2_rescue(const float* __restrict__ z,
                                                 const float* __restrict__ emb,
                                                 const int* __restrict__ ws_cnt,
                                                 const int* __restrict__ ws_list,
                                                 int* __restrict__ ws_idx) {
    __shared__ float  zrow[D];
    __shared__ double rv[256];
    __shared__ int    ri[256];
    const int cnt = *ws_cnt;
    for (int r = blockIdx.x; r < cnt; r += gridDim.x) {
        const int q = ws_list[r];
        __syncthreads();
        if (threadIdx.x < D) zrow[threadIdx.x] = z[(size_t)q * D + threadIdx.x];
        __syncthreads();
        double best = 1e300;
        int    bi   = 0x7fffffff;
        for (int c = threadIdx.x; c < K_CODES; c += 256) {
            const float4* er = (const float4*)(emb + (size_t)c * D);
            double acc = 0.0;
#pragma unroll
            for (int k = 0; k < 16; ++k) {
                float4 e  = er[k];
                double d0 = (double)zrow[4 * k + 0] - (double)e.x;
                double d1 = (double)zrow[4 * k + 1] - (double)e.y;
                double d2 = (double)zrow[4 * k + 2] - (double)e.z;
                double d3 = (double)zrow[4 * k + 3] - (double)e.w;
                acc += d0 * d0 + d1 * d1 + d2 * d2 + d3 * d3;
            }
            if (acc < best) { best = acc; bi = c; }
        }
        rv[threadIdx.x] = best;
        ri[threadIdx.x] = bi;
        __syncthreads();
        for (int s = 128; s > 0; s >>= 1) {
            if (threadIdx.x < s) {
                double ov = rv[threadIdx.x + s];
                int    oi = ri[threadIdx.x + s];
                if (ov < rv[threadIdx.x] || (ov == rv[threadIdx.x] && oi < ri[threadIdx.x])) {
                    rv[threadIdx.x] = ov;
                    ri[threadIdx.x] = oi;
                }
            }
            __syncthreads();
        }
        if (threadIdx.x == 0) ws_idx[q] = ri[0];
        __syncthreads();
    }
}

// ---- K3: gather z_q, emit idx as float, per-block loss partials ----
__global__ __launch_bounds__(256) void k3_gather(const float* __restrict__ emb,
                                                 const float* __restrict__ z,
                                                 const int* __restrict__ ws_idx,
                                                 float* __restrict__ out,
                                                 float* __restrict__ partial) {
    __shared__ float sb[256];
    int g = blockIdx.x * 256 + threadIdx.x;
    int q = g >> 6, d = g & 63;
    int id = ws_idx[q];
    float e = emb[(size_t)id * D + d];
    out[g] = e;
    if (d == 0) out[(size_t)M_QUERIES * D + q] = (float)id;
    float df = e - z[g];
    sb[threadIdx.x] = df * df;
    __syncthreads();
    for (int s = 128; s > 0; s >>= 1) {
        if (threadIdx.x < s) sb[threadIdx.x] += sb[threadIdx.x + s];
        __syncthreads();
    }
    if (threadIdx.x == 0) partial[blockIdx.x] = sb[0];
}

// ---- K4: final loss reduce ----
__global__ __launch_bounds__(256) void k4_loss(const float* __restrict__ partial,
                                               float* __restrict__ out) {
    __shared__ double sb[256];
    double s = 0.0;
    for (int i = threadIdx.x; i < (M_QUERIES * D) / 256; i += 256) s += (double)partial[i];
    sb[threadIdx.x] = s;
    __syncthreads();
    for (int st = 128; st > 0; st >>= 1) {
        if (threadIdx.x < st) sb[threadIdx.x] += sb[threadIdx.x + st];
        __syncthreads();
    }
    if (threadIdx.x == 0)
        out[(size_t)M_QUERIES * D + M_QUERIES] =
            (float)(1.25 * sb[0] / (double)((size_t)M_QUERIES * D));
}

extern "C" void kernel_launch(void* const* d_in, const int* in_sizes, int n_in,
                              void* d_out, int out_size, void* d_ws, size_t ws_size,
                              hipStream_t stream) {
    const float* z   = (const float*)d_in[0];
    const float* emb = (const float*)d_in[1];
    float* out = (float*)d_out;
    char*  ws  = (char*)d_ws;

    unsigned short* e_hi    = (unsigned short*)(ws);                    // 1 MB
    unsigned short* e_lo    = (unsigned short*)(ws + 1048576);          // 1 MB
    float*          halfee  = (float*)(ws + 2097152);                   // 32 KB
    float4*         ws_part = (float4*)(ws + 2129920);                  // 2 MB
    int*            ws_idx  = (int*)(ws + 2129920 + 2097152);           // 128 KB
    int*            ws_cnt  = (int*)(ws + 2129920 + 2097152 + 131072);  // 64 B
    int*            ws_list = (int*)(ws + 2129920 + 2097152 + 131136);  // 128 KB
    float*          partial = (float*)(ws + 2129920 + 2097152 + 262208);// 32 KB

    k0_split<<<K_CODES / 64, 256, 0, stream>>>(emb, e_hi, e_lo, halfee, ws_cnt);

    dim3 g1(M_QUERIES / QPB, SLICES);
    k1_mfma<<<g1, 256, 0, stream>>>(z, e_hi, e_lo, halfee, ws_part);

    k1b_merge<<<M_QUERIES / 256, 256, 0, stream>>>(ws_part, ws_idx, ws_cnt, ws_list);

    k2_rescue<<<256, 256, 0, stream>>>(z, emb, ws_cnt, ws_list, ws_idx);

    k3_gather<<<(M_QUERIES * D) / 256, 256, 0, stream>>>(emb, z, ws_idx, out, partial);

    k4_loss<<<1, 256, 0, stream>>>(partial, out);
}

// Round 12
// 196.145 us; speedup vs baseline: 1.4719x; 1.0133x over previous
//
#include <hip/hip_runtime.h>
#include <hip/hip_bf16.h>
#include <math.h>

#define D 64
#define K_CODES 8192
#define M_QUERIES 32768
#define SLICES 4
#define CODES_PER_SLICE (K_CODES / SLICES)  // 2048
#define CHUNK 64
#define NCHUNK (CODES_PER_SLICE / CHUNK)    // 32 chunks per slice
#define QPB 128                              // queries per block = 2 waves * 64
#define TAU_V 4e-3f                          // gap threshold in v units

typedef __attribute__((ext_vector_type(8))) short bf16x8;
typedef __attribute__((ext_vector_type(4))) float f32x4;
typedef __attribute__((ext_vector_type(16))) float f32x16;

__device__ __forceinline__ unsigned short f2bf(float x) {
    __hip_bfloat16 h = __float2bfloat16(x);
    return *reinterpret_cast<unsigned short*>(&h);
}
__device__ __forceinline__ float bf2f(unsigned short s) {
    __hip_bfloat16 h;
    *reinterpret_cast<unsigned short*>(&h) = s;
    return __bfloat162float(h);
}
__device__ __forceinline__ void gld_lds16(const void* g, void* l) {
    __builtin_amdgcn_global_load_lds(
        (const __attribute__((address_space(1))) void*)g,
        (__attribute__((address_space(3))) void*)l, 16, 0, 0);
}
__device__ __forceinline__ void gld_lds4(const void* g, void* l) {
    __builtin_amdgcn_global_load_lds(
        (const __attribute__((address_space(1))) void*)g,
        (__attribute__((address_space(3))) void*)l, 4, 0, 0);
}

// ---- K0: split emb into bf16 hi/lo in MFMA-FRAGMENT order ----
// Per 64-code chunk: [u=k-unit 0..7][code-in-chunk 0..63][16B]; byte offset
// chunk*8192 + (u*64 + r)*16 holds code r's elems u*8..u*8+7.
__global__ __launch_bounds__(256) void k0_split(const float* __restrict__ emb,
                                                unsigned short* __restrict__ e_hi,
                                                unsigned short* __restrict__ e_lo,
                                                float* __restrict__ halfee,
                                                int* __restrict__ ws_cnt) {
    const int t = threadIdx.x;
    const int chunk = blockIdx.x;
    if (chunk == 0 && t == 0) *ws_cnt = 0;
    const int u = t & 7;
#pragma unroll
    for (int it = 0; it < 2; ++it) {
        const int r = (t >> 3) + it * 32;           // code within chunk
        const float* src = emb + ((size_t)(chunk * 64 + r) * 64 + u * 8);
        float4 f0 = *(const float4*)(src);
        float4 f1 = *(const float4*)(src + 4);
        float f[8] = {f0.x, f0.y, f0.z, f0.w, f1.x, f1.y, f1.z, f1.w};
        bf16x8 h, lo;
        float s = 0.f;
#pragma unroll
        for (int j = 0; j < 8; ++j) {
            float e = f[j];
            s += e * e;
            unsigned short hh = f2bf(e);
            h[j]  = (short)hh;
            lo[j] = (short)f2bf(e - bf2f(hh));
        }
        size_t off = (size_t)chunk * 8192 + (size_t)(u * 64 + r) * 16;
        *(bf16x8*)((char*)e_hi + off) = h;
        *(bf16x8*)((char*)e_lo + off) = lo;
        s += __shfl_xor(s, 1);
        s += __shfl_xor(s, 2);
        s += __shfl_xor(s, 4);
        if (u == 0) halfee[chunk * 64 + r] = 0.5f * s + 128.0f;
    }
}

// ---- K1: 32x32x16 MFMA scoring, 64 queries/wave (2 B-frag groups/wave) ----
// Each A-fragment LDS read feeds BOTH query groups (6 MFMAs per 2 reads):
// LDS reads per query halved vs the 32-q/wave version (the round-8..11
// binding pipe). Tile-split (process codes 0-31 then 32-63) keeps only
// 32 acc VGPRs live. 128-thread blocks, grid (256,4) -> 4 blocks/CU.
__global__ __launch_bounds__(128, 1) void k1_mfma(const float* __restrict__ z,
                                                  const unsigned short* __restrict__ e_hi,
                                                  const unsigned short* __restrict__ e_lo,
                                                  const float* __restrict__ halfee,
                                                  float4* __restrict__ ws_part) {
    __shared__ __align__(16) unsigned short ldshi[2][CHUNK * 64];  // 8KB each buf
    __shared__ __align__(16) unsigned short ldslo[2][CHUNK * 64];
    __shared__ __align__(16) float ldshe[2][CHUNK];                // 256B each

    const int tid = threadIdx.x;
    const int wid = tid >> 6;    // 0..1
    const int l   = tid & 63;
    const int col = l & 31;
    const int hi  = l >> 5;
    const int slice = blockIdx.y;
    const int chunk0 = slice * NCHUNK;

    // 2 query groups of 32 per wave -> negated bf16 hi/lo B-fragments
    const int qw0 = blockIdx.x * QPB + wid * 64;
    bf16x8 qh[2][4], ql[2][4];
#pragma unroll
    for (int g = 0; g < 2; ++g) {
        const int qrow = qw0 + g * 32 + col;
#pragma unroll
        for (int kk = 0; kk < 4; ++kk) {
            const float* src = z + (size_t)qrow * D + kk * 16 + hi * 8;
            float4 f0 = *(const float4*)(src);
            float4 f1 = *(const float4*)(src + 4);
            float f[8] = {f0.x, f0.y, f0.z, f0.w, f1.x, f1.y, f1.z, f1.w};
            bf16x8 h, lo;
#pragma unroll
            for (int j = 0; j < 8; ++j) {
                float x = -f[j];
                unsigned short hh = f2bf(x);
                float r = x - bf2f(hh);
                h[j]  = (short)hh;
                lo[j] = (short)f2bf(r);
            }
            qh[g][kk] = h;
            ql[g][kk] = lo;
        }
    }

    float g1A = 1e30f, g2A = 1e30f; int giA = 0x7fffffff;
    float g1B = 1e30f, g2B = 1e30f; int giB = 0x7fffffff;

// staging: each wave covers 4KB of hi and 4KB of lo (4+4 gld_lds16);
// wave 0 stages the 256B he block.
#define STAGE(buf, c1)                                                           \
    {                                                                            \
        size_t cb = (size_t)(chunk0 + (c1)) * 8192 + wid * 4096 + l * 16;        \
        const char* ghi = (const char*)e_hi + cb;                                \
        const char* glo = (const char*)e_lo + cb;                                \
        char* dhi = (char*)&ldshi[buf][0] + wid * 4096;                          \
        char* dlo = (char*)&ldslo[buf][0] + wid * 4096;                          \
        _Pragma("unroll") for (int i = 0; i < 4; ++i) {                          \
            gld_lds16(ghi + i * 1024, dhi + i * 1024);                           \
            gld_lds16(glo + i * 1024, dlo + i * 1024);                           \
        }                                                                        \
        if (wid == 0)                                                            \
            gld_lds4((const char*)halfee + (size_t)(chunk0 + (c1)) * 256 + l * 4,\
                     (char*)&ldshe[buf][0]);                                     \
    }

#define TOP2(accX, g1X, g2X, giX, tile, cbase)                                   \
    {                                                                            \
        float m1p = 1e30f, m2p = 1e30f;                                          \
        _Pragma("unroll") for (int r = 0; r < 16; ++r) {                         \
            float vp = __int_as_float((__float_as_int(accX[r]) & 0xFFFFFFE0)     \
                                      | ((tile) * 16 + r));                      \
            m2p = __builtin_amdgcn_fmed3f(vp, m1p, m2p);                         \
            m1p = fminf(m1p, vp);                                                \
        }                                                                        \
        int p1 = __float_as_int(m1p) & 31;                                       \
        int rr = p1 & 15;                                                        \
        int code = (cbase) + (p1 >> 4) * 32 + (rr & 3) + 8 * (rr >> 2) + 4 * hi; \
        bool lt = m1p < g1X;                                                     \
        g2X = fminf(lt ? g1X : g2X, lt ? m2p : m1p);                             \
        g1X = lt ? m1p : g1X;                                                    \
        giX = lt ? code : giX;                                                   \
    }

#define COMPUTE(bufc, cbase)                                                     \
    {                                                                            \
        const char*  bh  = (const char*)ldshi[bufc];                             \
        const char*  bl  = (const char*)ldslo[bufc];                             \
        const float* bhe = ldshe[bufc];                                          \
        _Pragma("unroll") for (int tile = 0; tile < 2; ++tile) {                 \
            f32x16 accA, accB;                                                   \
            _Pragma("unroll") for (int g4 = 0; g4 < 4; ++g4) {                   \
                f32x4 he4 = *(const f32x4*)(bhe + tile * 32 + g4 * 8 + 4 * hi);  \
                _Pragma("unroll") for (int j = 0; j < 4; ++j) {                  \
                    accA[g4 * 4 + j] = he4[j];                                   \
                    accB[g4 * 4 + j] = he4[j];                                   \
                }                                                                \
            }                                                                    \
            _Pragma("unroll") for (int kk = 0; kk < 4; ++kk) {                   \
                int a0 = ((kk * 2 + hi) * 64 + col) * 16 + tile * 512;           \
                bf16x8 ah = *(const bf16x8*)(bh + a0);                           \
                bf16x8 al = *(const bf16x8*)(bl + a0);                           \
                accA = __builtin_amdgcn_mfma_f32_32x32x16_bf16(ah, qh[0][kk], accA, 0, 0, 0); \
                accB = __builtin_amdgcn_mfma_f32_32x32x16_bf16(ah, qh[1][kk], accB, 0, 0, 0); \
                accA = __builtin_amdgcn_mfma_f32_32x32x16_bf16(ah, ql[0][kk], accA, 0, 0, 0); \
                accB = __builtin_amdgcn_mfma_f32_32x32x16_bf16(ah, ql[1][kk], accB, 0, 0, 0); \
                accA = __builtin_amdgcn_mfma_f32_32x32x16_bf16(al, qh[0][kk], accA, 0, 0, 0); \
                accB = __builtin_amdgcn_mfma_f32_32x32x16_bf16(al, qh[1][kk], accB, 0, 0, 0); \
            }                                                                    \
            TOP2(accA, g1A, g2A, giA, tile, cbase);                              \
            TOP2(accB, g1B, g2B, giB, tile, cbase);                              \
        }                                                                        \
    }

    STAGE(0, 0);
    __syncthreads();
    for (int c = 0; c < NCHUNK; ++c) {
        const int cur = c & 1;
        if (c + 1 < NCHUNK) STAGE(cur ^ 1, c + 1);
        COMPUTE(cur, slice * CODES_PER_SLICE + c * CHUNK);
        __syncthreads();
    }

    // lanes l and l^32 share a query column, hold disjoint code rows
#pragma unroll
    for (int g = 0; g < 2; ++g) {
        float a1 = g ? g1B : g1A, a2 = g ? g2B : g2A;
        int   ai = g ? giB : giA;
        float o1 = __shfl_xor(a1, 32);
        float o2 = __shfl_xor(a2, 32);
        int   oi = __shfl_xor(ai, 32);
        bool  take = (o1 < a1) || (o1 == a1 && oi < ai);
        float n2   = take ? fminf(o2, a1) : fminf(a2, o1);
        a1 = take ? o1 : a1;
        ai = take ? oi : ai;
        a2 = n2;
        if (l < 32) {
            int q = qw0 + g * 32 + col;
            ws_part[(size_t)q * SLICES + slice] =
                make_float4(a1, a2, __int_as_float(ai), 0.f);
        }
    }
#undef STAGE
#undef TOP2
#undef COMPUTE
}

// ---- K1b: merge slices, flag near-ties ----
__global__ __launch_bounds__(256) void k1b_merge(const float4* __restrict__ ws_part,
                                                 int* __restrict__ ws_idx,
                                                 int* __restrict__ ws_cnt,
                                                 int* __restrict__ ws_list) {
    int q = blockIdx.x * blockDim.x + threadIdx.x;
    float m1 = 1e30f, m2 = 1e30f;
    int   i1 = 0x7fffffff;
#pragma unroll
    for (int s = 0; s < SLICES; ++s) {
        float4 p = ws_part[(size_t)q * SLICES + s];
        float v1 = p.x, v2 = p.y;
        int   vi = __float_as_int(p.z);
        if (v1 < m1 || (v1 == m1 && vi < i1)) { m2 = fminf(m1, v2); m1 = v1; i1 = vi; }
        else                                  { m2 = fminf(m2, v1); }
    }
    ws_idx[q] = i1;
    if (m2 - m1 < TAU_V) {
        int r = atomicAdd(ws_cnt, 1);
        ws_list[r] = q;
    }
}

// ---- K2: fp64 exact rescan for near-tie queries ----
__global__ __launch_bounds__(256) void k2_rescue(const float* __restrict__ z,
                                                 const float* __restrict__ emb,
                                                 const int* __restrict__ ws_cnt,
                                                 const int* __restrict__ ws_list,
                                                 int* __restrict__ ws_idx) {
    __shared__ float  zrow[D];
    __shared__ double rv[256];
    __shared__ int    ri[256];
    const int cnt = *ws_cnt;
    for (int r = blockIdx.x; r < cnt; r += gridDim.x) {
        const int q = ws_list[r];
        __syncthreads();
        if (threadIdx.x < D) zrow[threadIdx.x] = z[(size_t)q * D + threadIdx.x];
        __syncthreads();
        double best = 1e300;
        int    bi   = 0x7fffffff;
        for (int c = threadIdx.x; c < K_CODES; c += 256) {
            const float4* er = (const float4*)(emb + (size_t)c * D);
            double acc = 0.0;
#pragma unroll
            for (int k = 0; k < 16; ++k) {
                float4 e  = er[k];
                double d0 = (double)zrow[4 * k + 0] - (double)e.x;
                double d1 = (double)zrow[4 * k + 1] - (double)e.y;
                double d2 = (double)zrow[4 * k + 2] - (double)e.z;
                double d3 = (double)zrow[4 * k + 3] - (double)e.w;
                acc += d0 * d0 + d1 * d1 + d2 * d2 + d3 * d3;
            }
            if (acc < best) { best = acc; bi = c; }
        }
        rv[threadIdx.x] = best;
        ri[threadIdx.x] = bi;
        __syncthreads();
        for (int s = 128; s > 0; s >>= 1) {
            if (threadIdx.x < s) {
                double ov = rv[threadIdx.x + s];
                int    oi = ri[threadIdx.x + s];
                if (ov < rv[threadIdx.x] || (ov == rv[threadIdx.x] && oi < ri[threadIdx.x])) {
                    rv[threadIdx.x] = ov;
                    ri[threadIdx.x] = oi;
                }
            }
            __syncthreads();
        }
        if (threadIdx.x == 0) ws_idx[q] = ri[0];
        __syncthreads();
    }
}

// ---- K3: gather z_q, emit idx as float, per-block loss partials ----
__global__ __launch_bounds__(256) void k3_gather(const float* __restrict__ emb,
                                                 const float* __restrict__ z,
                                                 const int* __restrict__ ws_idx,
                                                 float* __restrict__ out,
                                                 float* __restrict__ partial) {
    __shared__ float sb[256];
    int g = blockIdx.x * 256 + threadIdx.x;
    int q = g >> 6, d = g & 63;
    int id = ws_idx[q];
    float e = emb[(size_t)id * D + d];
    out[g] = e;
    if (d == 0) out[(size_t)M_QUERIES * D + q] = (float)id;
    float df = e - z[g];
    sb[threadIdx.x] = df * df;
    __syncthreads();
    for (int s = 128; s > 0; s >>= 1) {
        if (threadIdx.x < s) sb[threadIdx.x] += sb[threadIdx.x + s];
        __syncthreads();
    }
    if (threadIdx.x == 0) partial[blockIdx.x] = sb[0];
}

// ---- K4: final loss reduce ----
__global__ __launch_bounds__(256) void k4_loss(const float* __restrict__ partial,
                                               float* __restrict__ out) {
    __shared__ double sb[256];
    double s = 0.0;
    for (int i = threadIdx.x; i < (M_QUERIES * D) / 256; i += 256) s += (double)partial[i];
    sb[threadIdx.x] = s;
    __syncthreads();
    for (int st = 128; st > 0; st >>= 1) {
        if (threadIdx.x < st) sb[threadIdx.x] += sb[threadIdx.x + st];
        __syncthreads();
    }
    if (threadIdx.x == 0)
        out[(size_t)M_QUERIES * D + M_QUERIES] =
            (float)(1.25 * sb[0] / (double)((size_t)M_QUERIES * D));
}

extern "C" void kernel_launch(void* const* d_in, const int* in_sizes, int n_in,
                              void* d_out, int out_size, void* d_ws, size_t ws_size,
                              hipStream_t stream) {
    const float* z   = (const float*)d_in[0];
    const float* emb = (const float*)d_in[1];
    float* out = (float*)d_out;
    char*  ws  = (char*)d_ws;

    unsigned short* e_hi    = (unsigned short*)(ws);                    // 1 MB
    unsigned short* e_lo    = (unsigned short*)(ws + 1048576);          // 1 MB
    float*          halfee  = (float*)(ws + 2097152);                   // 32 KB
    float4*         ws_part = (float4*)(ws + 2129920);                  // 2 MB
    int*            ws_idx  = (int*)(ws + 2129920 + 2097152);           // 128 KB
    int*            ws_cnt  = (int*)(ws + 2129920 + 2097152 + 131072);  // 64 B
    int*            ws_list = (int*)(ws + 2129920 + 2097152 + 131136);  // 128 KB
    float*          partial = (float*)(ws + 2129920 + 2097152 + 262208);// 32 KB

    k0_split<<<K_CODES / 64, 256, 0, stream>>>(emb, e_hi, e_lo, halfee, ws_cnt);

    dim3 g1(M_QUERIES / QPB, SLICES);
    k1_mfma<<<g1, 128, 0, stream>>>(z, e_hi, e_lo, halfee, ws_part);

    k1b_merge<<<M_QUERIES / 256, 256, 0, stream>>>(ws_part, ws_idx, ws_cnt, ws_list);

    k2_rescue<<<256, 256, 0, stream>>>(z, emb, ws_cnt, ws_list, ws_idx);

    k3_gather<<<(M_QUERIES * D) / 256, 256, 0, stream>>>(emb, z, ws_idx, out, partial);

    k4_loss<<<1, 256, 0, stream>>>(partial, out);
}

// Round 13
// 194.227 us; speedup vs baseline: 1.4865x; 1.0099x over previous
//
#include <hip/hip_runtime.h>
#include <hip/hip_bf16.h>
#include <math.h>

#define D 64
#define K_CODES 8192
#define M_QUERIES 32768
#define SLICES 8
#define CODES_PER_SLICE (K_CODES / SLICES)  // 1024
#define CHUNK 64
#define NCHUNK (CODES_PER_SLICE / CHUNK)    // 16 chunks per slice
#define QPB 256                              // queries per block = 4 waves * 64
#define TAU_V 4e-3f                          // gap threshold in v units

typedef __attribute__((ext_vector_type(8))) short bf16x8;
typedef __attribute__((ext_vector_type(4))) float f32x4;
typedef __attribute__((ext_vector_type(16))) float f32x16;

__device__ __forceinline__ unsigned short f2bf(float x) {
    __hip_bfloat16 h = __float2bfloat16(x);
    return *reinterpret_cast<unsigned short*>(&h);
}
__device__ __forceinline__ float bf2f(unsigned short s) {
    __hip_bfloat16 h;
    *reinterpret_cast<unsigned short*>(&h) = s;
    return __bfloat162float(h);
}
__device__ __forceinline__ void gld_lds16(const void* g, void* l) {
    __builtin_amdgcn_global_load_lds(
        (const __attribute__((address_space(1))) void*)g,
        (__attribute__((address_space(3))) void*)l, 16, 0, 0);
}
__device__ __forceinline__ void gld_lds4(const void* g, void* l) {
    __builtin_amdgcn_global_load_lds(
        (const __attribute__((address_space(1))) void*)g,
        (__attribute__((address_space(3))) void*)l, 4, 0, 0);
}

// ---- K0: split emb into bf16 hi/lo in MFMA-FRAGMENT order ----
// Per 64-code chunk: [u=k-unit 0..7][code-in-chunk 0..63][16B]; byte offset
// chunk*8192 + (u*64 + r)*16 holds code r's elems u*8..u*8+7.
__global__ __launch_bounds__(256) void k0_split(const float* __restrict__ emb,
                                                unsigned short* __restrict__ e_hi,
                                                unsigned short* __restrict__ e_lo,
                                                float* __restrict__ halfee,
                                                int* __restrict__ ws_cnt) {
    const int t = threadIdx.x;
    const int chunk = blockIdx.x;
    if (chunk == 0 && t == 0) *ws_cnt = 0;
    const int u = t & 7;
#pragma unroll
    for (int it = 0; it < 2; ++it) {
        const int r = (t >> 3) + it * 32;           // code within chunk
        const float* src = emb + ((size_t)(chunk * 64 + r) * 64 + u * 8);
        float4 f0 = *(const float4*)(src);
        float4 f1 = *(const float4*)(src + 4);
        float f[8] = {f0.x, f0.y, f0.z, f0.w, f1.x, f1.y, f1.z, f1.w};
        bf16x8 h, lo;
        float s = 0.f;
#pragma unroll
        for (int j = 0; j < 8; ++j) {
            float e = f[j];
            s += e * e;
            unsigned short hh = f2bf(e);
            h[j]  = (short)hh;
            lo[j] = (short)f2bf(e - bf2f(hh));
        }
        size_t off = (size_t)chunk * 8192 + (size_t)(u * 64 + r) * 16;
        *(bf16x8*)((char*)e_hi + off) = h;
        *(bf16x8*)((char*)e_lo + off) = lo;
        s += __shfl_xor(s, 1);
        s += __shfl_xor(s, 2);
        s += __shfl_xor(s, 4);
        if (u == 0) halfee[chunk * 64 + r] = 0.5f * s + 128.0f;
    }
}

// ---- K1: 32x32x16 MFMA scoring, 64 queries/wave, 4 waves/block ----
// r12 lesson: the binder is MFMA-pipe starvation from low occupancy, not LDS.
// Keep the 64-q/wave reuse COMPUTE (each A-frag read feeds 2 query groups)
// but at 256-thread blocks + SLICES=8 -> grid 1024 -> 4 blocks/CU (33KB LDS)
// -> 16 waves/CU = 4 waves/SIMD (2x round 12).
__global__ __launch_bounds__(256, 1) void k1_mfma(const float* __restrict__ z,
                                                  const unsigned short* __restrict__ e_hi,
                                                  const unsigned short* __restrict__ e_lo,
                                                  const float* __restrict__ halfee,
                                                  float4* __restrict__ ws_part) {
    __shared__ __align__(16) unsigned short ldshi[2][CHUNK * 64];  // 8KB each buf
    __shared__ __align__(16) unsigned short ldslo[2][CHUNK * 64];
    __shared__ __align__(16) float ldshe[2][CHUNK];                // 256B each

    const int tid = threadIdx.x;
    const int wid = tid >> 6;    // 0..3
    const int l   = tid & 63;
    const int col = l & 31;
    const int hi  = l >> 5;
    const int slice = blockIdx.y;
    const int chunk0 = slice * NCHUNK;

    // 2 query groups of 32 per wave -> negated bf16 hi/lo B-fragments
    const int qw0 = blockIdx.x * QPB + wid * 64;
    bf16x8 qh[2][4], ql[2][4];
#pragma unroll
    for (int g = 0; g < 2; ++g) {
        const int qrow = qw0 + g * 32 + col;
#pragma unroll
        for (int kk = 0; kk < 4; ++kk) {
            const float* src = z + (size_t)qrow * D + kk * 16 + hi * 8;
            float4 f0 = *(const float4*)(src);
            float4 f1 = *(const float4*)(src + 4);
            float f[8] = {f0.x, f0.y, f0.z, f0.w, f1.x, f1.y, f1.z, f1.w};
            bf16x8 h, lo;
#pragma unroll
            for (int j = 0; j < 8; ++j) {
                float x = -f[j];
                unsigned short hh = f2bf(x);
                float r = x - bf2f(hh);
                h[j]  = (short)hh;
                lo[j] = (short)f2bf(r);
            }
            qh[g][kk] = h;
            ql[g][kk] = lo;
        }
    }

    float g1A = 1e30f, g2A = 1e30f; int giA = 0x7fffffff;
    float g1B = 1e30f, g2B = 1e30f; int giB = 0x7fffffff;

// staging: 4 waves split the 16.5KB chunk: each wave 2KB hi (2 loads) +
// 2KB lo (2 loads); wave 0 stages the 256B he block.
#define STAGE(buf, c1)                                                           \
    {                                                                            \
        size_t cb = (size_t)(chunk0 + (c1)) * 8192 + wid * 2048 + l * 16;        \
        const char* ghi = (const char*)e_hi + cb;                                \
        const char* glo = (const char*)e_lo + cb;                                \
        char* dhi = (char*)&ldshi[buf][0] + wid * 2048;                          \
        char* dlo = (char*)&ldslo[buf][0] + wid * 2048;                          \
        gld_lds16(ghi, dhi);                                                     \
        gld_lds16(ghi + 1024, dhi + 1024);                                       \
        gld_lds16(glo, dlo);                                                     \
        gld_lds16(glo + 1024, dlo + 1024);                                       \
        if (wid == 0)                                                            \
            gld_lds4((const char*)halfee + (size_t)(chunk0 + (c1)) * 256 + l * 4,\
                     (char*)&ldshe[buf][0]);                                     \
    }

#define TOP2(accX, g1X, g2X, giX, tile, cbase)                                   \
    {                                                                            \
        float m1p = 1e30f, m2p = 1e30f;                                          \
        _Pragma("unroll") for (int r = 0; r < 16; ++r) {                         \
            float vp = __int_as_float((__float_as_int(accX[r]) & 0xFFFFFFE0)     \
                                      | ((tile) * 16 + r));                      \
            m2p = __builtin_amdgcn_fmed3f(vp, m1p, m2p);                         \
            m1p = fminf(m1p, vp);                                                \
        }                                                                        \
        int p1 = __float_as_int(m1p) & 31;                                       \
        int rr = p1 & 15;                                                        \
        int code = (cbase) + (p1 >> 4) * 32 + (rr & 3) + 8 * (rr >> 2) + 4 * hi; \
        bool lt = m1p < g1X;                                                     \
        g2X = fminf(lt ? g1X : g2X, lt ? m2p : m1p);                             \
        g1X = lt ? m1p : g1X;                                                    \
        giX = lt ? code : giX;                                                   \
    }

#define COMPUTE(bufc, cbase)                                                     \
    {                                                                            \
        const char*  bh  = (const char*)ldshi[bufc];                             \
        const char*  bl  = (const char*)ldslo[bufc];                             \
        const float* bhe = ldshe[bufc];                                          \
        _Pragma("unroll") for (int tile = 0; tile < 2; ++tile) {                 \
            f32x16 accA, accB;                                                   \
            _Pragma("unroll") for (int g4 = 0; g4 < 4; ++g4) {                   \
                f32x4 he4 = *(const f32x4*)(bhe + tile * 32 + g4 * 8 + 4 * hi);  \
                _Pragma("unroll") for (int j = 0; j < 4; ++j) {                  \
                    accA[g4 * 4 + j] = he4[j];                                   \
                    accB[g4 * 4 + j] = he4[j];                                   \
                }                                                                \
            }                                                                    \
            _Pragma("unroll") for (int kk = 0; kk < 4; ++kk) {                   \
                int a0 = ((kk * 2 + hi) * 64 + col) * 16 + tile * 512;           \
                bf16x8 ah = *(const bf16x8*)(bh + a0);                           \
                bf16x8 al = *(const bf16x8*)(bl + a0);                           \
                accA = __builtin_amdgcn_mfma_f32_32x32x16_bf16(ah, qh[0][kk], accA, 0, 0, 0); \
                accB = __builtin_amdgcn_mfma_f32_32x32x16_bf16(ah, qh[1][kk], accB, 0, 0, 0); \
                accA = __builtin_amdgcn_mfma_f32_32x32x16_bf16(ah, ql[0][kk], accA, 0, 0, 0); \
                accB = __builtin_amdgcn_mfma_f32_32x32x16_bf16(ah, ql[1][kk], accB, 0, 0, 0); \
                accA = __builtin_amdgcn_mfma_f32_32x32x16_bf16(al, qh[0][kk], accA, 0, 0, 0); \
                accB = __builtin_amdgcn_mfma_f32_32x32x16_bf16(al, qh[1][kk], accB, 0, 0, 0); \
            }                                                                    \
            TOP2(accA, g1A, g2A, giA, tile, cbase);                              \
            TOP2(accB, g1B, g2B, giB, tile, cbase);                              \
        }                                                                        \
    }

    STAGE(0, 0);
    __syncthreads();
    for (int c = 0; c < NCHUNK; ++c) {
        const int cur = c & 1;
        if (c + 1 < NCHUNK) STAGE(cur ^ 1, c + 1);
        COMPUTE(cur, slice * CODES_PER_SLICE + c * CHUNK);
        __syncthreads();
    }

    // lanes l and l^32 share a query column, hold disjoint code rows
#pragma unroll
    for (int g = 0; g < 2; ++g) {
        float a1 = g ? g1B : g1A, a2 = g ? g2B : g2A;
        int   ai = g ? giB : giA;
        float o1 = __shfl_xor(a1, 32);
        float o2 = __shfl_xor(a2, 32);
        int   oi = __shfl_xor(ai, 32);
        bool  take = (o1 < a1) || (o1 == a1 && oi < ai);
        float n2   = take ? fminf(o2, a1) : fminf(a2, o1);
        a1 = take ? o1 : a1;
        ai = take ? oi : ai;
        a2 = n2;
        if (l < 32) {
            int q = qw0 + g * 32 + col;
            ws_part[(size_t)q * SLICES + slice] =
                make_float4(a1, a2, __int_as_float(ai), 0.f);
        }
    }
#undef STAGE
#undef TOP2
#undef COMPUTE
}

// ---- K1b: merge slices, flag near-ties ----
__global__ __launch_bounds__(256) void k1b_merge(const float4* __restrict__ ws_part,
                                                 int* __restrict__ ws_idx,
                                                 int* __restrict__ ws_cnt,
                                                 int* __restrict__ ws_list) {
    int q = blockIdx.x * blockDim.x + threadIdx.x;
    float m1 = 1e30f, m2 = 1e30f;
    int   i1 = 0x7fffffff;
#pragma unroll
    for (int s = 0; s < SLICES; ++s) {
        float4 p = ws_part[(size_t)q * SLICES + s];
        float v1 = p.x, v2 = p.y;
        int   vi = __float_as_int(p.z);
        if (v1 < m1 || (v1 == m1 && vi < i1)) { m2 = fminf(m1, v2); m1 = v1; i1 = vi; }
        else                                  { m2 = fminf(m2, v1); }
    }
    ws_idx[q] = i1;
    if (m2 - m1 < TAU_V) {
        int r = atomicAdd(ws_cnt, 1);
        ws_list[r] = q;
    }
}

// ---- K2: fp64 exact rescan for near-tie queries ----
__global__ __launch_bounds__(256) void k2_rescue(const float* __restrict__ z,
                                                 const float* __restrict__ emb,
                                                 const int* __restrict__ ws_cnt,
                                                 const int* __restrict__ ws_list,
                                                 int* __restrict__ ws_idx) {
    __shared__ float  zrow[D];
    __shared__ double rv[256];
    __shared__ int    ri[256];
    const int cnt = *ws_cnt;
    for (int r = blockIdx.x; r < cnt; r += gridDim.x) {
        const int q = ws_list[r];
        __syncthreads();
        if (threadIdx.x < D) zrow[threadIdx.x] = z[(size_t)q * D + threadIdx.x];
        __syncthreads();
        double best = 1e300;
        int    bi   = 0x7fffffff;
        for (int c = threadIdx.x; c < K_CODES; c += 256) {
            const float4* er = (const float4*)(emb + (size_t)c * D);
            double acc = 0.0;
#pragma unroll
            for (int k = 0; k < 16; ++k) {
                float4 e  = er[k];
                double d0 = (double)zrow[4 * k + 0] - (double)e.x;
                double d1 = (double)zrow[4 * k + 1] - (double)e.y;
                double d2 = (double)zrow[4 * k + 2] - (double)e.z;
                double d3 = (double)zrow[4 * k + 3] - (double)e.w;
                acc += d0 * d0 + d1 * d1 + d2 * d2 + d3 * d3;
            }
            if (acc < best) { best = acc; bi = c; }
        }
        rv[threadIdx.x] = best;
        ri[threadIdx.x] = bi;
        __syncthreads();
        for (int s = 128; s > 0; s >>= 1) {
            if (threadIdx.x < s) {
                double ov = rv[threadIdx.x + s];
                int    oi = ri[threadIdx.x + s];
                if (ov < rv[threadIdx.x] || (ov == rv[threadIdx.x] && oi < ri[threadIdx.x])) {
                    rv[threadIdx.x] = ov;
                    ri[threadIdx.x] = oi;
                }
            }
            __syncthreads();
        }
        if (threadIdx.x == 0) ws_idx[q] = ri[0];
        __syncthreads();
    }
}

// ---- K3: gather z_q, emit idx as float, per-block loss partials ----
__global__ __launch_bounds__(256) void k3_gather(const float* __restrict__ emb,
                                                 const float* __restrict__ z,
                                                 const int* __restrict__ ws_idx,
                                                 float* __restrict__ out,
                                                 float* __restrict__ partial) {
    __shared__ float sb[256];
    int g = blockIdx.x * 256 + threadIdx.x;
    int q = g >> 6, d = g & 63;
    int id = ws_idx[q];
    float e = emb[(size_t)id * D + d];
    out[g] = e;
    if (d == 0) out[(size_t)M_QUERIES * D + q] = (float)id;
    float df = e - z[g];
    sb[threadIdx.x] = df * df;
    __syncthreads();
    for (int s = 128; s > 0; s >>= 1) {
        if (threadIdx.x < s) sb[threadIdx.x] += sb[threadIdx.x + s];
        __syncthreads();
    }
    if (threadIdx.x == 0) partial[blockIdx.x] = sb[0];
}

// ---- K4: final loss reduce ----
__global__ __launch_bounds__(256) void k4_loss(const float* __restrict__ partial,
                                               float* __restrict__ out) {
    __shared__ double sb[256];
    double s = 0.0;
    for (int i = threadIdx.x; i < (M_QUERIES * D) / 256; i += 256) s += (double)partial[i];
    sb[threadIdx.x] = s;
    __syncthreads();
    for (int st = 128; st > 0; st >>= 1) {
        if (threadIdx.x < st) sb[threadIdx.x] += sb[threadIdx.x + st];
        __syncthreads();
    }
    if (threadIdx.x == 0)
        out[(size_t)M_QUERIES * D + M_QUERIES] =
            (float)(1.25 * sb[0] / (double)((size_t)M_QUERIES * D));
}

extern "C" void kernel_launch(void* const* d_in, const int* in_sizes, int n_in,
                              void* d_out, int out_size, void* d_ws, size_t ws_size,
                              hipStream_t stream) {
    const float* z   = (const float*)d_in[0];
    const float* emb = (const float*)d_in[1];
    float* out = (float*)d_out;
    char*  ws  = (char*)d_ws;

    unsigned short* e_hi    = (unsigned short*)(ws);                    // 1 MB
    unsigned short* e_lo    = (unsigned short*)(ws + 1048576);          // 1 MB
    float*          halfee  = (float*)(ws + 2097152);                   // 32 KB
    float4*         ws_part = (float4*)(ws + 2129920);                  // 4 MB (8 slices)
    int*            ws_idx  = (int*)(ws + 2129920 + 4194304);           // 128 KB
    int*            ws_cnt  = (int*)(ws + 2129920 + 4194304 + 131072);  // 64 B
    int*            ws_list = (int*)(ws + 2129920 + 4194304 + 131136);  // 128 KB
    float*          partial = (float*)(ws + 2129920 + 4194304 + 262208);// 32 KB

    k0_split<<<K_CODES / 64, 256, 0, stream>>>(emb, e_hi, e_lo, halfee, ws_cnt);

    dim3 g1(M_QUERIES / QPB, SLICES);
    k1_mfma<<<g1, 256, 0, stream>>>(z, e_hi, e_lo, halfee, ws_part);

    k1b_merge<<<M_QUERIES / 256, 256, 0, stream>>>(ws_part, ws_idx, ws_cnt, ws_list);

    k2_rescue<<<256, 256, 0, stream>>>(z, emb, ws_cnt, ws_list, ws_idx);

    k3_gather<<<(M_QUERIES * D) / 256, 256, 0, stream>>>(emb, z, ws_idx, out, partial);

    k4_loss<<<1, 256, 0, stream>>>(partial, out);
}

// Round 14
// 193.937 us; speedup vs baseline: 1.4887x; 1.0015x over previous
//
#include <hip/hip_runtime.h>
#include <hip/hip_bf16.h>
#include <math.h>

#define D 64
#define K_CODES 8192
#define M_QUERIES 32768
#define SLICES 8
#define CODES_PER_SLICE (K_CODES / SLICES)  // 1024
#define CHUNK 32
#define NCHUNK (CODES_PER_SLICE / CHUNK)    // 32 chunks per slice
#define QPB 256                              // queries per block = 4 waves * 64
#define TAU_V 4e-3f                          // gap threshold in v units

typedef __attribute__((ext_vector_type(8))) short bf16x8;
typedef __attribute__((ext_vector_type(4))) float f32x4;
typedef __attribute__((ext_vector_type(16))) float f32x16;

__device__ __forceinline__ unsigned short f2bf(float x) {
    __hip_bfloat16 h = __float2bfloat16(x);
    return *reinterpret_cast<unsigned short*>(&h);
}
__device__ __forceinline__ float bf2f(unsigned short s) {
    __hip_bfloat16 h;
    *reinterpret_cast<unsigned short*>(&h) = s;
    return __bfloat162float(h);
}
__device__ __forceinline__ void gld_lds16(const void* g, void* l) {
    __builtin_amdgcn_global_load_lds(
        (const __attribute__((address_space(1))) void*)g,
        (__attribute__((address_space(3))) void*)l, 16, 0, 0);
}
__device__ __forceinline__ void gld_lds4(const void* g, void* l) {
    __builtin_amdgcn_global_load_lds(
        (const __attribute__((address_space(1))) void*)g,
        (__attribute__((address_space(3))) void*)l, 4, 0, 0);
}

// ---- K0: split emb into bf16 hi/lo in MFMA-FRAGMENT order, 32-code chunks ----
// Per 32-code chunk: [u=k-unit 0..7][code-in-chunk 0..31][16B]; byte offset
// c32*4096 + (u*32 + r32)*16 holds code's elems u*8..u*8+7.
__global__ __launch_bounds__(256) void k0_split(const float* __restrict__ emb,
                                                unsigned short* __restrict__ e_hi,
                                                unsigned short* __restrict__ e_lo,
                                                float* __restrict__ halfee,
                                                int* __restrict__ ws_cnt) {
    const int t = threadIdx.x;
    const int grp = blockIdx.x;                 // 64-code group
    if (grp == 0 && t == 0) *ws_cnt = 0;
    const int u = t & 7;
#pragma unroll
    for (int it = 0; it < 2; ++it) {
        const int r = (t >> 3) + it * 32;       // code within 64-group
        const int code = grp * 64 + r;
        const float* src = emb + ((size_t)code * 64 + u * 8);
        float4 f0 = *(const float4*)(src);
        float4 f1 = *(const float4*)(src + 4);
        float f[8] = {f0.x, f0.y, f0.z, f0.w, f1.x, f1.y, f1.z, f1.w};
        bf16x8 h, lo;
        float s = 0.f;
#pragma unroll
        for (int j = 0; j < 8; ++j) {
            float e = f[j];
            s += e * e;
            unsigned short hh = f2bf(e);
            h[j]  = (short)hh;
            lo[j] = (short)f2bf(e - bf2f(hh));
        }
        const int c32 = code >> 5, r32 = code & 31;
        size_t off = (size_t)c32 * 4096 + (size_t)(u * 32 + r32) * 16;
        *(bf16x8*)((char*)e_hi + off) = h;
        *(bf16x8*)((char*)e_lo + off) = lo;
        s += __shfl_xor(s, 1);
        s += __shfl_xor(s, 2);
        s += __shfl_xor(s, 4);
        if (u == 0) halfee[code] = 0.5f * s + 128.0f;
    }
}

// ---- K1: 32x32x16 MFMA scoring, 64 queries/wave, CHUNK=32 (16.5KB LDS) ----
// r13 lesson: block residency tracks LDS as if only ~64KB/CU were allocatable
// (r9's 16KB kernel hit 37.6% occupancy; 33KB kernels stick at ~19-27%).
// Halve LDS: CHUNK=32, dbuf = 2*(4KB+4KB+128B) = 16.5KB -> target ~4 blocks/CU.
__global__ __launch_bounds__(256, 1) void k1_mfma(const float* __restrict__ z,
                                                  const unsigned short* __restrict__ e_hi,
                                                  const unsigned short* __restrict__ e_lo,
                                                  const float* __restrict__ halfee,
                                                  float4* __restrict__ ws_part) {
    __shared__ __align__(16) unsigned short ldshi[2][CHUNK * 64];  // 4KB each buf
    __shared__ __align__(16) unsigned short ldslo[2][CHUNK * 64];
    __shared__ __align__(16) float ldshe[2][CHUNK];                // 128B each

    const int tid = threadIdx.x;
    const int wid = tid >> 6;    // 0..3
    const int l   = tid & 63;
    const int col = l & 31;
    const int hi  = l >> 5;
    const int slice = blockIdx.y;
    const int chunk0 = slice * NCHUNK;   // global 32-chunk base

    // 2 query groups of 32 per wave -> negated bf16 hi/lo B-fragments
    const int qw0 = blockIdx.x * QPB + wid * 64;
    bf16x8 qh[2][4], ql[2][4];
#pragma unroll
    for (int g = 0; g < 2; ++g) {
        const int qrow = qw0 + g * 32 + col;
#pragma unroll
        for (int kk = 0; kk < 4; ++kk) {
            const float* src = z + (size_t)qrow * D + kk * 16 + hi * 8;
            float4 f0 = *(const float4*)(src);
            float4 f1 = *(const float4*)(src + 4);
            float f[8] = {f0.x, f0.y, f0.z, f0.w, f1.x, f1.y, f1.z, f1.w};
            bf16x8 h, lo;
#pragma unroll
            for (int j = 0; j < 8; ++j) {
                float x = -f[j];
                unsigned short hh = f2bf(x);
                float r = x - bf2f(hh);
                h[j]  = (short)hh;
                lo[j] = (short)f2bf(r);
            }
            qh[g][kk] = h;
            ql[g][kk] = lo;
        }
    }

    float g1A = 1e30f, g2A = 1e30f; int giA = 0x7fffffff;
    float g1B = 1e30f, g2B = 1e30f; int giB = 0x7fffffff;

// staging: per wave 1KB hi (1 load) + 1KB lo (1 load); lanes 0-31 of wave 0
// stage the 128B he block (exec-masked gld_lds4).
#define STAGE(buf, c1)                                                           \
    {                                                                            \
        size_t cb = (size_t)(chunk0 + (c1)) * 4096 + wid * 1024 + l * 16;        \
        gld_lds16((const char*)e_hi + cb, (char*)&ldshi[buf][0] + wid * 1024);   \
        gld_lds16((const char*)e_lo + cb, (char*)&ldslo[buf][0] + wid * 1024);   \
        if (tid < 32)                                                            \
            gld_lds4((const char*)halfee + (size_t)(chunk0 + (c1)) * 128 + tid * 4, \
                     (char*)&ldshe[buf][0]);                                     \
    }

#define TOP2(accX, g1X, g2X, giX, cbase)                                         \
    {                                                                            \
        float m1p = 1e30f, m2p = 1e30f;                                          \
        _Pragma("unroll") for (int r = 0; r < 16; ++r) {                         \
            float vp = __int_as_float((__float_as_int(accX[r]) & 0xFFFFFFF0) | r); \
            m2p = __builtin_amdgcn_fmed3f(vp, m1p, m2p);                         \
            m1p = fminf(m1p, vp);                                                \
        }                                                                        \
        int p1 = __float_as_int(m1p) & 15;                                       \
        int code = (cbase) + (p1 & 3) + 8 * (p1 >> 2) + 4 * hi;                  \
        bool lt = m1p < g1X;                                                     \
        g2X = fminf(lt ? g1X : g2X, lt ? m2p : m1p);                             \
        g1X = lt ? m1p : g1X;                                                    \
        giX = lt ? code : giX;                                                   \
    }

#define COMPUTE(bufc, cbase)                                                     \
    {                                                                            \
        const char*  bh  = (const char*)ldshi[bufc];                             \
        const char*  bl  = (const char*)ldslo[bufc];                             \
        const float* bhe = ldshe[bufc];                                          \
        f32x16 accA, accB;                                                       \
        _Pragma("unroll") for (int g4 = 0; g4 < 4; ++g4) {                       \
            f32x4 he4 = *(const f32x4*)(bhe + g4 * 8 + 4 * hi);                  \
            _Pragma("unroll") for (int j = 0; j < 4; ++j) {                      \
                accA[g4 * 4 + j] = he4[j];                                       \
                accB[g4 * 4 + j] = he4[j];                                       \
            }                                                                    \
        }                                                                        \
        _Pragma("unroll") for (int kk = 0; kk < 4; ++kk) {                       \
            int a0 = ((kk * 2 + hi) * 32 + col) * 16;   /* lane-contiguous */    \
            bf16x8 ah = *(const bf16x8*)(bh + a0);                               \
            bf16x8 al = *(const bf16x8*)(bl + a0);                               \
            accA = __builtin_amdgcn_mfma_f32_32x32x16_bf16(ah, qh[0][kk], accA, 0, 0, 0); \
            accB = __builtin_amdgcn_mfma_f32_32x32x16_bf16(ah, qh[1][kk], accB, 0, 0, 0); \
            accA = __builtin_amdgcn_mfma_f32_32x32x16_bf16(ah, ql[0][kk], accA, 0, 0, 0); \
            accB = __builtin_amdgcn_mfma_f32_32x32x16_bf16(ah, ql[1][kk], accB, 0, 0, 0); \
            accA = __builtin_amdgcn_mfma_f32_32x32x16_bf16(al, qh[0][kk], accA, 0, 0, 0); \
            accB = __builtin_amdgcn_mfma_f32_32x32x16_bf16(al, qh[1][kk], accB, 0, 0, 0); \
        }                                                                        \
        TOP2(accA, g1A, g2A, giA, cbase);                                        \
        TOP2(accB, g1B, g2B, giB, cbase);                                        \
    }

    STAGE(0, 0);
    __syncthreads();
    for (int c = 0; c < NCHUNK; ++c) {
        const int cur = c & 1;
        if (c + 1 < NCHUNK) STAGE(cur ^ 1, c + 1);
        COMPUTE(cur, slice * CODES_PER_SLICE + c * CHUNK);
        __syncthreads();
    }

    // lanes l and l^32 share a query column, hold disjoint code rows
#pragma unroll
    for (int g = 0; g < 2; ++g) {
        float a1 = g ? g1B : g1A, a2 = g ? g2B : g2A;
        int   ai = g ? giB : giA;
        float o1 = __shfl_xor(a1, 32);
        float o2 = __shfl_xor(a2, 32);
        int   oi = __shfl_xor(ai, 32);
        bool  take = (o1 < a1) || (o1 == a1 && oi < ai);
        float n2   = take ? fminf(o2, a1) : fminf(a2, o1);
        a1 = take ? o1 : a1;
        ai = take ? oi : ai;
        a2 = n2;
        if (l < 32) {
            int q = qw0 + g * 32 + col;
            ws_part[(size_t)q * SLICES + slice] =
                make_float4(a1, a2, __int_as_float(ai), 0.f);
        }
    }
#undef STAGE
#undef TOP2
#undef COMPUTE
}

// ---- K1b: merge slices, flag near-ties ----
__global__ __launch_bounds__(256) void k1b_merge(const float4* __restrict__ ws_part,
                                                 int* __restrict__ ws_idx,
                                                 int* __restrict__ ws_cnt,
                                                 int* __restrict__ ws_list) {
    int q = blockIdx.x * blockDim.x + threadIdx.x;
    float m1 = 1e30f, m2 = 1e30f;
    int   i1 = 0x7fffffff;
#pragma unroll
    for (int s = 0; s < SLICES; ++s) {
        float4 p = ws_part[(size_t)q * SLICES + s];
        float v1 = p.x, v2 = p.y;
        int   vi = __float_as_int(p.z);
        if (v1 < m1 || (v1 == m1 && vi < i1)) { m2 = fminf(m1, v2); m1 = v1; i1 = vi; }
        else                                  { m2 = fminf(m2, v1); }
    }
    ws_idx[q] = i1;
    if (m2 - m1 < TAU_V) {
        int r = atomicAdd(ws_cnt, 1);
        ws_list[r] = q;
    }
}

// ---- K2: fp64 exact rescan for near-tie queries ----
__global__ __launch_bounds__(256) void k2_rescue(const float* __restrict__ z,
                                                 const float* __restrict__ emb,
                                                 const int* __restrict__ ws_cnt,
                                                 const int* __restrict__ ws_list,
                                                 int* __restrict__ ws_idx) {
    __shared__ float  zrow[D];
    __shared__ double rv[256];
    __shared__ int    ri[256];
    const int cnt = *ws_cnt;
    for (int r = blockIdx.x; r < cnt; r += gridDim.x) {
        const int q = ws_list[r];
        __syncthreads();
        if (threadIdx.x < D) zrow[threadIdx.x] = z[(size_t)q * D + threadIdx.x];
        __syncthreads();
        double best = 1e300;
        int    bi   = 0x7fffffff;
        for (int c = threadIdx.x; c < K_CODES; c += 256) {
            const float4* er = (const float4*)(emb + (size_t)c * D);
            double acc = 0.0;
#pragma unroll
            for (int k = 0; k < 16; ++k) {
                float4 e  = er[k];
                double d0 = (double)zrow[4 * k + 0] - (double)e.x;
                double d1 = (double)zrow[4 * k + 1] - (double)e.y;
                double d2 = (double)zrow[4 * k + 2] - (double)e.z;
                double d3 = (double)zrow[4 * k + 3] - (double)e.w;
                acc += d0 * d0 + d1 * d1 + d2 * d2 + d3 * d3;
            }
            if (acc < best) { best = acc; bi = c; }
        }
        rv[threadIdx.x] = best;
        ri[threadIdx.x] = bi;
        __syncthreads();
        for (int s = 128; s > 0; s >>= 1) {
            if (threadIdx.x < s) {
                double ov = rv[threadIdx.x + s];
                int    oi = ri[threadIdx.x + s];
                if (ov < rv[threadIdx.x] || (ov == rv[threadIdx.x] && oi < ri[threadIdx.x])) {
                    rv[threadIdx.x] = ov;
                    ri[threadIdx.x] = oi;
                }
            }
            __syncthreads();
        }
        if (threadIdx.x == 0) ws_idx[q] = ri[0];
        __syncthreads();
    }
}

// ---- K3: gather z_q, emit idx as float, per-block loss partials ----
__global__ __launch_bounds__(256) void k3_gather(const float* __restrict__ emb,
                                                 const float* __restrict__ z,
                                                 const int* __restrict__ ws_idx,
                                                 float* __restrict__ out,
                                                 float* __restrict__ partial) {
    __shared__ float sb[256];
    int g = blockIdx.x * 256 + threadIdx.x;
    int q = g >> 6, d = g & 63;
    int id = ws_idx[q];
    float e = emb[(size_t)id * D + d];
    out[g] = e;
    if (d == 0) out[(size_t)M_QUERIES * D + q] = (float)id;
    float df = e - z[g];
    sb[threadIdx.x] = df * df;
    __syncthreads();
    for (int s = 128; s > 0; s >>= 1) {
        if (threadIdx.x < s) sb[threadIdx.x] += sb[threadIdx.x + s];
        __syncthreads();
    }
    if (threadIdx.x == 0) partial[blockIdx.x] = sb[0];
}

// ---- K4: final loss reduce ----
__global__ __launch_bounds__(256) void k4_loss(const float* __restrict__ partial,
                                               float* __restrict__ out) {
    __shared__ double sb[256];
    double s = 0.0;
    for (int i = threadIdx.x; i < (M_QUERIES * D) / 256; i += 256) s += (double)partial[i];
    sb[threadIdx.x] = s;
    __syncthreads();
    for (int st = 128; st > 0; st >>= 1) {
        if (threadIdx.x < st) sb[threadIdx.x] += sb[threadIdx.x + st];
        __syncthreads();
    }
    if (threadIdx.x == 0)
        out[(size_t)M_QUERIES * D + M_QUERIES] =
            (float)(1.25 * sb[0] / (double)((size_t)M_QUERIES * D));
}

extern "C" void kernel_launch(void* const* d_in, const int* in_sizes, int n_in,
                              void* d_out, int out_size, void* d_ws, size_t ws_size,
                              hipStream_t stream) {
    const float* z   = (const float*)d_in[0];
    const float* emb = (const float*)d_in[1];
    float* out = (float*)d_out;
    char*  ws  = (char*)d_ws;

    unsigned short* e_hi    = (unsigned short*)(ws);                    // 1 MB
    unsigned short* e_lo    = (unsigned short*)(ws + 1048576);          // 1 MB
    float*          halfee  = (float*)(ws + 2097152);                   // 32 KB
    float4*         ws_part = (float4*)(ws + 2129920);                  // 4 MB (8 slices)
    int*            ws_idx  = (int*)(ws + 2129920 + 4194304);           // 128 KB
    int*            ws_cnt  = (int*)(ws + 2129920 + 4194304 + 131072);  // 64 B
    int*            ws_list = (int*)(ws + 2129920 + 4194304 + 131136);  // 128 KB
    float*          partial = (float*)(ws + 2129920 + 4194304 + 262208);// 32 KB

    k0_split<<<K_CODES / 64, 256, 0, stream>>>(emb, e_hi, e_lo, halfee, ws_cnt);

    dim3 g1(M_QUERIES / QPB, SLICES);
    k1_mfma<<<g1, 256, 0, stream>>>(z, e_hi, e_lo, halfee, ws_part);

    k1b_merge<<<M_QUERIES / 256, 256, 0, stream>>>(ws_part, ws_idx, ws_cnt, ws_list);

    k2_rescue<<<256, 256, 0, stream>>>(z, emb, ws_cnt, ws_list, ws_idx);

    k3_gather<<<(M_QUERIES * D) / 256, 256, 0, stream>>>(emb, z, ws_idx, out, partial);

    k4_loss<<<1, 256, 0, stream>>>(partial, out);
}

// Round 15
// 188.566 us; speedup vs baseline: 1.5311x; 1.0285x over previous
//
#include <hip/hip_runtime.h>
#include <hip/hip_bf16.h>
#include <math.h>

#define D 64
#define K_CODES 8192
#define M_QUERIES 32768
#define SLICES 8
#define CODES_PER_SLICE (K_CODES / SLICES)  // 1024
#define CHUNK 32
#define NCHUNK (CODES_PER_SLICE / CHUNK)    // 32 chunks per slice
#define QPB 512                              // queries per block = 8 waves * 64
#define TAU_V 4e-3f                          // gap threshold in v units

typedef __attribute__((ext_vector_type(8))) short bf16x8;
typedef __attribute__((ext_vector_type(4))) float f32x4;
typedef __attribute__((ext_vector_type(16))) float f32x16;

__device__ __forceinline__ unsigned short f2bf(float x) {
    __hip_bfloat16 h = __float2bfloat16(x);
    return *reinterpret_cast<unsigned short*>(&h);
}
__device__ __forceinline__ float bf2f(unsigned short s) {
    __hip_bfloat16 h;
    *reinterpret_cast<unsigned short*>(&h) = s;
    return __bfloat162float(h);
}
__device__ __forceinline__ void gld_lds16(const void* g, void* l) {
    __builtin_amdgcn_global_load_lds(
        (const __attribute__((address_space(1))) void*)g,
        (__attribute__((address_space(3))) void*)l, 16, 0, 0);
}
__device__ __forceinline__ void gld_lds4(const void* g, void* l) {
    __builtin_amdgcn_global_load_lds(
        (const __attribute__((address_space(1))) void*)g,
        (__attribute__((address_space(3))) void*)l, 4, 0, 0);
}

// ---- K0: split emb into bf16 hi/lo in MFMA-FRAGMENT order, 32-code chunks ----
// Per 32-code chunk: [u=k-unit 0..7][code-in-chunk 0..31][16B]; byte offset
// c32*4096 + (u*32 + r32)*16 holds code's elems u*8..u*8+7.
__global__ __launch_bounds__(256) void k0_split(const float* __restrict__ emb,
                                                unsigned short* __restrict__ e_hi,
                                                unsigned short* __restrict__ e_lo,
                                                float* __restrict__ halfee,
                                                int* __restrict__ ws_cnt) {
    const int t = threadIdx.x;
    const int grp = blockIdx.x;                 // 64-code group
    if (grp == 0 && t == 0) *ws_cnt = 0;
    const int u = t & 7;
#pragma unroll
    for (int it = 0; it < 2; ++it) {
        const int r = (t >> 3) + it * 32;       // code within 64-group
        const int code = grp * 64 + r;
        const float* src = emb + ((size_t)code * 64 + u * 8);
        float4 f0 = *(const float4*)(src);
        float4 f1 = *(const float4*)(src + 4);
        float f[8] = {f0.x, f0.y, f0.z, f0.w, f1.x, f1.y, f1.z, f1.w};
        bf16x8 h, lo;
        float s = 0.f;
#pragma unroll
        for (int j = 0; j < 8; ++j) {
            float e = f[j];
            s += e * e;
            unsigned short hh = f2bf(e);
            h[j]  = (short)hh;
            lo[j] = (short)f2bf(e - bf2f(hh));
        }
        const int c32 = code >> 5, r32 = code & 31;
        size_t off = (size_t)c32 * 4096 + (size_t)(u * 32 + r32) * 16;
        *(bf16x8*)((char*)e_hi + off) = h;
        *(bf16x8*)((char*)e_lo + off) = lo;
        s += __shfl_xor(s, 1);
        s += __shfl_xor(s, 2);
        s += __shfl_xor(s, 4);
        if (u == 0) halfee[code] = 0.5f * s + 128.0f;
    }
}

// ---- K1: 32x32x16 MFMA scoring, 64 queries/wave, 8 waves/block ----
// Plateau diagnosis (r8..r14): wall = 2.6x MFMA floor with ~2 waves/SIMD
// resident, invariant to LDS/VALU cuts -> wave-residency-bound. Probe: pack
// 8 waves into each block (512 thr), grid 512 = exactly 2 blocks/CU. If
// residency was block-count-bound this gives 16 waves/CU = 4 waves/SIMD.
__global__ __launch_bounds__(512, 1) void k1_mfma(const float* __restrict__ z,
                                                  const unsigned short* __restrict__ e_hi,
                                                  const unsigned short* __restrict__ e_lo,
                                                  const float* __restrict__ halfee,
                                                  float4* __restrict__ ws_part) {
    __shared__ __align__(16) unsigned short ldshi[2][CHUNK * 64];  // 4KB each buf
    __shared__ __align__(16) unsigned short ldslo[2][CHUNK * 64];
    __shared__ __align__(16) float ldshe[2][CHUNK];                // 128B each

    const int tid = threadIdx.x;
    const int wid = tid >> 6;    // 0..7
    const int l   = tid & 63;
    const int col = l & 31;
    const int hi  = l >> 5;
    const int slice = blockIdx.y;
    const int chunk0 = slice * NCHUNK;   // global 32-chunk base

    // 2 query groups of 32 per wave -> negated bf16 hi/lo B-fragments
    const int qw0 = blockIdx.x * QPB + wid * 64;
    bf16x8 qh[2][4], ql[2][4];
#pragma unroll
    for (int g = 0; g < 2; ++g) {
        const int qrow = qw0 + g * 32 + col;
#pragma unroll
        for (int kk = 0; kk < 4; ++kk) {
            const float* src = z + (size_t)qrow * D + kk * 16 + hi * 8;
            float4 f0 = *(const float4*)(src);
            float4 f1 = *(const float4*)(src + 4);
            float f[8] = {f0.x, f0.y, f0.z, f0.w, f1.x, f1.y, f1.z, f1.w};
            bf16x8 h, lo;
#pragma unroll
            for (int j = 0; j < 8; ++j) {
                float x = -f[j];
                unsigned short hh = f2bf(x);
                float r = x - bf2f(hh);
                h[j]  = (short)hh;
                lo[j] = (short)f2bf(r);
            }
            qh[g][kk] = h;
            ql[g][kk] = lo;
        }
    }

    float g1A = 1e30f, g2A = 1e30f; int giA = 0x7fffffff;
    float g1B = 1e30f, g2B = 1e30f; int giB = 0x7fffffff;

// staging: waves 0-3 stage hi (1KB each), waves 4-7 stage lo (1KB each);
// lanes 0-31 of wave 0 stage the 128B he block. One gld_lds16 per wave.
#define STAGE(buf, c1)                                                           \
    {                                                                            \
        size_t cb = (size_t)(chunk0 + (c1)) * 4096 + (size_t)(wid & 3) * 1024 + l * 16; \
        const char* gsrc = (wid < 4 ? (const char*)e_hi : (const char*)e_lo) + cb; \
        char* dst = (wid < 4 ? (char*)&ldshi[buf][0] : (char*)&ldslo[buf][0])    \
                    + (wid & 3) * 1024;                                          \
        gld_lds16(gsrc, dst);                                                    \
        if (tid < 32)                                                            \
            gld_lds4((const char*)halfee + (size_t)(chunk0 + (c1)) * 128 + tid * 4, \
                     (char*)&ldshe[buf][0]);                                     \
    }

#define TOP2(accX, g1X, g2X, giX, cbase)                                         \
    {                                                                            \
        float m1p = 1e30f, m2p = 1e30f;                                          \
        _Pragma("unroll") for (int r = 0; r < 16; ++r) {                         \
            float vp = __int_as_float((__float_as_int(accX[r]) & 0xFFFFFFF0) | r); \
            m2p = __builtin_amdgcn_fmed3f(vp, m1p, m2p);                         \
            m1p = fminf(m1p, vp);                                                \
        }                                                                        \
        int p1 = __float_as_int(m1p) & 15;                                       \
        int code = (cbase) + (p1 & 3) + 8 * (p1 >> 2) + 4 * hi;                  \
        bool lt = m1p < g1X;                                                     \
        g2X = fminf(lt ? g1X : g2X, lt ? m2p : m1p);                             \
        g1X = lt ? m1p : g1X;                                                    \
        giX = lt ? code : giX;                                                   \
    }

#define COMPUTE(bufc, cbase)                                                     \
    {                                                                            \
        const char*  bh  = (const char*)ldshi[bufc];                             \
        const char*  bl  = (const char*)ldslo[bufc];                             \
        const float* bhe = ldshe[bufc];                                          \
        f32x16 accA, accB;                                                       \
        _Pragma("unroll") for (int g4 = 0; g4 < 4; ++g4) {                       \
            f32x4 he4 = *(const f32x4*)(bhe + g4 * 8 + 4 * hi);                  \
            _Pragma("unroll") for (int j = 0; j < 4; ++j) {                      \
                accA[g4 * 4 + j] = he4[j];                                       \
                accB[g4 * 4 + j] = he4[j];                                       \
            }                                                                    \
        }                                                                        \
        _Pragma("unroll") for (int kk = 0; kk < 4; ++kk) {                       \
            int a0 = ((kk * 2 + hi) * 32 + col) * 16;   /* lane-contiguous */    \
            bf16x8 ah = *(const bf16x8*)(bh + a0);                               \
            bf16x8 al = *(const bf16x8*)(bl + a0);                               \
            accA = __builtin_amdgcn_mfma_f32_32x32x16_bf16(ah, qh[0][kk], accA, 0, 0, 0); \
            accB = __builtin_amdgcn_mfma_f32_32x32x16_bf16(ah, qh[1][kk], accB, 0, 0, 0); \
            accA = __builtin_amdgcn_mfma_f32_32x32x16_bf16(ah, ql[0][kk], accA, 0, 0, 0); \
            accB = __builtin_amdgcn_mfma_f32_32x32x16_bf16(ah, ql[1][kk], accB, 0, 0, 0); \
            accA = __builtin_amdgcn_mfma_f32_32x32x16_bf16(al, qh[0][kk], accA, 0, 0, 0); \
            accB = __builtin_amdgcn_mfma_f32_32x32x16_bf16(al, qh[1][kk], accB, 0, 0, 0); \
        }                                                                        \
        TOP2(accA, g1A, g2A, giA, cbase);                                        \
        TOP2(accB, g1B, g2B, giB, cbase);                                        \
    }

    STAGE(0, 0);
    __syncthreads();
    for (int c = 0; c < NCHUNK; ++c) {
        const int cur = c & 1;
        if (c + 1 < NCHUNK) STAGE(cur ^ 1, c + 1);
        COMPUTE(cur, slice * CODES_PER_SLICE + c * CHUNK);
        __syncthreads();
    }

    // lanes l and l^32 share a query column, hold disjoint code rows
#pragma unroll
    for (int g = 0; g < 2; ++g) {
        float a1 = g ? g1B : g1A, a2 = g ? g2B : g2A;
        int   ai = g ? giB : giA;
        float o1 = __shfl_xor(a1, 32);
        float o2 = __shfl_xor(a2, 32);
        int   oi = __shfl_xor(ai, 32);
        bool  take = (o1 < a1) || (o1 == a1 && oi < ai);
        float n2   = take ? fminf(o2, a1) : fminf(a2, o1);
        a1 = take ? o1 : a1;
        ai = take ? oi : ai;
        a2 = n2;
        if (l < 32) {
            int q = qw0 + g * 32 + col;
            ws_part[(size_t)q * SLICES + slice] =
                make_float4(a1, a2, __int_as_float(ai), 0.f);
        }
    }
#undef STAGE
#undef TOP2
#undef COMPUTE
}

// ---- K1b: merge slices, flag near-ties ----
__global__ __launch_bounds__(256) void k1b_merge(const float4* __restrict__ ws_part,
                                                 int* __restrict__ ws_idx,
                                                 int* __restrict__ ws_cnt,
                                                 int* __restrict__ ws_list) {
    int q = blockIdx.x * blockDim.x + threadIdx.x;
    float m1 = 1e30f, m2 = 1e30f;
    int   i1 = 0x7fffffff;
#pragma unroll
    for (int s = 0; s < SLICES; ++s) {
        float4 p = ws_part[(size_t)q * SLICES + s];
        float v1 = p.x, v2 = p.y;
        int   vi = __float_as_int(p.z);
        if (v1 < m1 || (v1 == m1 && vi < i1)) { m2 = fminf(m1, v2); m1 = v1; i1 = vi; }
        else                                  { m2 = fminf(m2, v1); }
    }
    ws_idx[q] = i1;
    if (m2 - m1 < TAU_V) {
        int r = atomicAdd(ws_cnt, 1);
        ws_list[r] = q;
    }
}

// ---- K2: fp64 exact rescan for near-tie queries ----
__global__ __launch_bounds__(256) void k2_rescue(const float* __restrict__ z,
                                                 const float* __restrict__ emb,
                                                 const int* __restrict__ ws_cnt,
                                                 const int* __restrict__ ws_list,
                                                 int* __restrict__ ws_idx) {
    __shared__ float  zrow[D];
    __shared__ double rv[256];
    __shared__ int    ri[256];
    const int cnt = *ws_cnt;
    for (int r = blockIdx.x; r < cnt; r += gridDim.x) {
        const int q = ws_list[r];
        __syncthreads();
        if (threadIdx.x < D) zrow[threadIdx.x] = z[(size_t)q * D + threadIdx.x];
        __syncthreads();
        double best = 1e300;
        int    bi   = 0x7fffffff;
        for (int c = threadIdx.x; c < K_CODES; c += 256) {
            const float4* er = (const float4*)(emb + (size_t)c * D);
            double acc = 0.0;
#pragma unroll
            for (int k = 0; k < 16; ++k) {
                float4 e  = er[k];
                double d0 = (double)zrow[4 * k + 0] - (double)e.x;
                double d1 = (double)zrow[4 * k + 1] - (double)e.y;
                double d2 = (double)zrow[4 * k + 2] - (double)e.z;
                double d3 = (double)zrow[4 * k + 3] - (double)e.w;
                acc += d0 * d0 + d1 * d1 + d2 * d2 + d3 * d3;
            }
            if (acc < best) { best = acc; bi = c; }
        }
        rv[threadIdx.x] = best;
        ri[threadIdx.x] = bi;
        __syncthreads();
        for (int s = 128; s > 0; s >>= 1) {
            if (threadIdx.x < s) {
                double ov = rv[threadIdx.x + s];
                int    oi = ri[threadIdx.x + s];
                if (ov < rv[threadIdx.x] || (ov == rv[threadIdx.x] && oi < ri[threadIdx.x])) {
                    rv[threadIdx.x] = ov;
                    ri[threadIdx.x] = oi;
                }
            }
            __syncthreads();
        }
        if (threadIdx.x == 0) ws_idx[q] = ri[0];
        __syncthreads();
    }
}

// ---- K3: gather z_q, emit idx as float, per-block loss partials ----
__global__ __launch_bounds__(256) void k3_gather(const float* __restrict__ emb,
                                                 const float* __restrict__ z,
                                                 const int* __restrict__ ws_idx,
                                                 float* __restrict__ out,
                                                 float* __restrict__ partial) {
    __shared__ float sb[256];
    int g = blockIdx.x * 256 + threadIdx.x;
    int q = g >> 6, d = g & 63;
    int id = ws_idx[q];
    float e = emb[(size_t)id * D + d];
    out[g] = e;
    if (d == 0) out[(size_t)M_QUERIES * D + q] = (float)id;
    float df = e - z[g];
    sb[threadIdx.x] = df * df;
    __syncthreads();
    for (int s = 128; s > 0; s >>= 1) {
        if (threadIdx.x < s) sb[threadIdx.x] += sb[threadIdx.x + s];
        __syncthreads();
    }
    if (threadIdx.x == 0) partial[blockIdx.x] = sb[0];
}

// ---- K4: final loss reduce ----
__global__ __launch_bounds__(256) void k4_loss(const float* __restrict__ partial,
                                               float* __restrict__ out) {
    __shared__ double sb[256];
    double s = 0.0;
    for (int i = threadIdx.x; i < (M_QUERIES * D) / 256; i += 256) s += (double)partial[i];
    sb[threadIdx.x] = s;
    __syncthreads();
    for (int st = 128; st > 0; st >>= 1) {
        if (threadIdx.x < st) sb[threadIdx.x] += sb[threadIdx.x + st];
        __syncthreads();
    }
    if (threadIdx.x == 0)
        out[(size_t)M_QUERIES * D + M_QUERIES] =
            (float)(1.25 * sb[0] / (double)((size_t)M_QUERIES * D));
}

extern "C" void kernel_launch(void* const* d_in, const int* in_sizes, int n_in,
                              void* d_out, int out_size, void* d_ws, size_t ws_size,
                              hipStream_t stream) {
    const float* z   = (const float*)d_in[0];
    const float* emb = (const float*)d_in[1];
    float* out = (float*)d_out;
    char*  ws  = (char*)d_ws;

    unsigned short* e_hi    = (unsigned short*)(ws);                    // 1 MB
    unsigned short* e_lo    = (unsigned short*)(ws + 1048576);          // 1 MB
    float*          halfee  = (float*)(ws + 2097152);                   // 32 KB
    float4*         ws_part = (float4*)(ws + 2129920);                  // 4 MB (8 slices)
    int*            ws_idx  = (int*)(ws + 2129920 + 4194304);           // 128 KB
    int*            ws_cnt  = (int*)(ws + 2129920 + 4194304 + 131072);  // 64 B
    int*            ws_list = (int*)(ws + 2129920 + 4194304 + 131136);  // 128 KB
    float*          partial = (float*)(ws + 2129920 + 4194304 + 262208);// 32 KB

    k0_split<<<K_CODES / 64, 256, 0, stream>>>(emb, e_hi, e_lo, halfee, ws_cnt);

    dim3 g1(M_QUERIES / QPB, SLICES);   // (64, 8) = 512 blocks of 512 threads
    k1_mfma<<<g1, 512, 0, stream>>>(z, e_hi, e_lo, halfee, ws_part);

    k1b_merge<<<M_QUERIES / 256, 256, 0, stream>>>(ws_part, ws_idx, ws_cnt, ws_list);

    k2_rescue<<<256, 256, 0, stream>>>(z, emb, ws_cnt, ws_list, ws_idx);

    k3_gather<<<(M_QUERIES * D) / 256, 256, 0, stream>>>(emb, z, ws_idx, out, partial);

    k4_loss<<<1, 256, 0, stream>>>(partial, out);
}